// Round 8
// baseline (5745.536 us; speedup 1.0000x reference)
//
#include <hip/hip_runtime.h>
#include <math.h>

#define L 9216
#define HH 96
#define WW 96
#define CC 256
#define CR 64
#define NCLUST 128
#define WIN 144
#define NK 64   // L/WIN

typedef float f32x4 __attribute__((ext_vector_type(4)));
typedef short s8v __attribute__((ext_vector_type(8)));
typedef short s4v __attribute__((ext_vector_type(4)));

static __device__ __forceinline__ short f2bf(float x) {
  union { float f; unsigned u; } v; v.f = x;
  unsigned r = (v.u + 0x7FFF + ((v.u >> 16) & 1)) >> 16;
  return (short)r;
}

// ---------------- K0: weight transpose wm[oc][ic*9+tap] -> wt[ic*9+tap][oc] ----------------
__global__ __launch_bounds__(256) void k_wprep(const float* __restrict__ wm,
                                               float* __restrict__ wt) {
  int idx = blockIdx.x * 256 + threadIdx.x;
  if (idx < 2304 * 64) {
    int oc = idx & 63, r = idx >> 6;
    wt[r * 64 + oc] = wm[(size_t)oc * 2304 + r];
  }
}

// ---------------- K1: conv3x3 (pad=1), IC split in 4 quarters ----------------
// grid (48 row-pairs, 4 ich, 8 b); 256 thr = 2 rows x (16 ocg x 8 colg); tile 4 oc x 12 col.
// 16 chunks of 4 ic; dbuf LDS; input early-load->late-write; weights via global_load_lds.
__global__ __launch_bounds__(256, 4) void k_conv3(const float* __restrict__ in,
                                                  const float* __restrict__ wt,
                                                  const float* __restrict__ bm,
                                                  float* __restrict__ xe,
                                                  float* __restrict__ xp) {
  int hp = blockIdx.x, ich = blockIdx.y, b = blockIdx.z;
  int h0 = hp * 2;
  __shared__ __align__(16) float in_s[2][4][4][100];  // [buf][ic][row][col] 12.8 KB
  __shared__ __align__(16) float w_s[2][36][64];      // [buf][ic*9+tap][oc] 18.4 KB, linear
  int t = threadIdx.x;
  int rowi = t >> 7, u = t & 127;
  int ocg = u & 15, colg = u >> 4;
  int oc0 = ocg * 4, c0 = colg * 12;

  float acc[4][12];
#pragma unroll
  for (int j = 0; j < 4; ++j) {
    float bv = ich ? 0.f : bm[oc0 + j];
#pragma unroll
    for (int i = 0; i < 12; ++i) acc[j][i] = bv;
  }

  const float* inb = in + (size_t)b * CC * L + (size_t)ich * 64 * L;
  const float* wtb = wt + (size_t)ich * 64 * 9 * 64;

  // one-time input staging address precompute: idx = t + q*256 over [0,1600)
  int offs[7];
  unsigned vmask = 0;
#pragma unroll
  for (int q = 0; q < 7; ++q) {
    int idx = t + q * 256;
    int ic = idx / 400, rem = idx % 400;
    int r = rem / 100, s = rem % 100;
    int gr = h0 - 1 + r, gc = s - 1;
    bool ok = (idx < 1600) && gr >= 0 && gr < HH && gc >= 0 && gc < WW;
    offs[q] = ic * L + gr * WW + gc;
    if (ok) vmask |= (1u << q);
  }

  float rg[7];
  auto LOADIN = [&](int icc) {
    size_t base = (size_t)icc * 4 * L;
#pragma unroll
    for (int q = 0; q < 7; ++q)
      rg[q] = ((vmask >> q) & 1) ? inb[base + offs[q]] : 0.f;
  };
  auto WRITEIN = [&](int buf) {
    float* ibase = &in_s[buf][0][0][0];
#pragma unroll
    for (int q = 0; q < 6; ++q) ibase[t + q * 256] = rg[q];
    if (t < 64) ibase[t + 1536] = rg[6];
  };
  auto STAGEW = [&](int icc, int buf) {
    const char* src = (const char*)(wtb + (size_t)icc * 2304);
    char* dst = (char*)&w_s[buf][0][0];
#pragma unroll
    for (int q = 0; q < 2; ++q)
      __builtin_amdgcn_global_load_lds(
          (const __attribute__((address_space(1))) void*)(src + q * 4096 + t * 16),
          (__attribute__((address_space(3))) void*)(dst + q * 4096 + t * 16), 16, 0, 0);
    if (t < 64)
      __builtin_amdgcn_global_load_lds(
          (const __attribute__((address_space(1))) void*)(src + 8192 + t * 16),
          (__attribute__((address_space(3))) void*)(dst + 8192 + t * 16), 16, 0, 0);
  };
  auto COMPUTE = [&](int buf) {
#pragma unroll
    for (int ic = 0; ic < 4; ++ic)
#pragma unroll
      for (int kh = 0; kh < 3; ++kh) {
        float ivf[16];
#pragma unroll
        for (int q = 0; q < 4; ++q)
          *(f32x4*)&ivf[q * 4] = *(const f32x4*)&in_s[buf][ic][rowi + kh][c0 + q * 4];
#pragma unroll
        for (int kw = 0; kw < 3; ++kw) {
          f32x4 wv = *(const f32x4*)&w_s[buf][ic * 9 + kh * 3 + kw][oc0];
#pragma unroll
          for (int j = 0; j < 4; ++j) {
            float wj = wv[j];
#pragma unroll
            for (int i = 0; i < 12; ++i) acc[j][i] += wj * ivf[i + kw];
          }
        }
      }
  };

  LOADIN(0);
  WRITEIN(0);
  STAGEW(0, 0);
  __syncthreads();
#pragma unroll 1
  for (int c = 0; c < 16; ++c) {
    int buf = c & 1;
    if (c < 15) LOADIN(c + 1);
    COMPUTE(buf);
    if (c < 15) {
      WRITEIN(buf ^ 1);
      STAGEW(c + 1, buf ^ 1);
    }
    __syncthreads();
  }

  float* dst = ich ? (xp + (size_t)(ich - 1) * 4718592ull) : xe;
  int lbase = (h0 + rowi) * WW + c0;
#pragma unroll
  for (int i = 0; i < 12; ++i) {
    f32x4 o = {acc[0][i], acc[1][i], acc[2][i], acc[3][i]};
    *(f32x4*)&dst[((size_t)b * L + lbase + i) * CR + oc0] = o;
  }
}

// ---------------- K1b: x_embed += xp0 + xp1 + xp2 ----------------
__global__ __launch_bounds__(256) void k_xred(float* __restrict__ xe,
                                              const float* __restrict__ xp) {
  int idx = blockIdx.x * 256 + threadIdx.x;
  if (idx < 1179648) {
    f32x4 a = *(const f32x4*)&xe[idx * 4];
    a += *(const f32x4*)&xp[idx * 4];
    a += *(const f32x4*)&xp[4718592ull + idx * 4];
    a += *(const f32x4*)&xp[9437184ull + idx * 4];
    *(f32x4*)&xe[idx * 4] = a;
  }
}

// ---------------- K2: conv1x1 -> y_embed[b][l][256] ----------------
__global__ __launch_bounds__(256) void k_conv1(const float* __restrict__ in,
                                               const float* __restrict__ wa,
                                               const float* __restrict__ ba,
                                               float* __restrict__ ye) {
  int lt = blockIdx.x, ot = blockIdx.y, b = blockIdx.z;
  int l0 = lt * 64, ocb = ot * 64;
  __shared__ float in_s[32 * 64];
  __shared__ float w_s[32 * 66];
  int t = threadIdx.x;
  int ocg = t & 15, pg = t >> 4;
  int oc0 = ocg * 4, px0 = pg * 4;
  float acc[4][4];
  for (int p = 0; p < 4; ++p)
    for (int j = 0; j < 4; ++j) acc[p][j] = ba[ocb + oc0 + j];
  const float* inb = in + (size_t)b * CC * L;
  for (int icc = 0; icc < 8; ++icc) {
    int ic0 = icc * 32;
    for (int e = t; e < 2048; e += 256) {
      int ic = e >> 6, px = e & 63;
      in_s[ic * 64 + px] = inb[(size_t)(ic0 + ic) * L + l0 + px];
    }
    for (int e = t; e < 2048; e += 256) {
      int oc = e >> 5, ic = e & 31;
      w_s[ic * 66 + oc] = wa[(size_t)(ocb + oc) * CC + ic0 + ic];
    }
    __syncthreads();
    for (int ic = 0; ic < 32; ++ic) {
      float w0v = w_s[ic * 66 + oc0 + 0];
      float w1v = w_s[ic * 66 + oc0 + 1];
      float w2v = w_s[ic * 66 + oc0 + 2];
      float w3v = w_s[ic * 66 + oc0 + 3];
      float4 xv = *(float4*)&in_s[ic * 64 + px0];
      acc[0][0] += xv.x * w0v; acc[0][1] += xv.x * w1v; acc[0][2] += xv.x * w2v; acc[0][3] += xv.x * w3v;
      acc[1][0] += xv.y * w0v; acc[1][1] += xv.y * w1v; acc[1][2] += xv.y * w2v; acc[1][3] += xv.y * w3v;
      acc[2][0] += xv.z * w0v; acc[2][1] += xv.z * w1v; acc[2][2] += xv.z * w2v; acc[2][3] += xv.z * w3v;
      acc[3][0] += xv.w * w0v; acc[3][1] += xv.w * w1v; acc[3][2] += xv.w * w2v; acc[3][3] += xv.w * w3v;
    }
    __syncthreads();
  }
  for (int p = 0; p < 4; ++p) {
    float4 o;
    o.x = acc[p][0]; o.y = acc[p][1]; o.z = acc[p][2]; o.w = acc[p][3];
    *(float4*)&ye[((size_t)b * L + l0 + px0 + p) * CC + ocb + oc0] = o;
  }
}

// ---------------- K3: buckets = argmax_c(x . mean_c) ----------------
__global__ __launch_bounds__(256) void k_bucket(const float* __restrict__ xe,
                                                const float* __restrict__ means,
                                                int* __restrict__ buckets) {
  int lt = blockIdx.x, b = blockIdx.y;
  int l0 = lt * 32;
  __shared__ float x_s[32 * 65];
  __shared__ float m_s[128 * 65];
  __shared__ float bv_s[32 * 8];
  __shared__ int bi_s[32 * 8];
  int t = threadIdx.x;
  for (int e = t; e < 2048; e += 256) {
    int px = e >> 6, d = e & 63;
    x_s[px * 65 + d] = xe[((size_t)b * L + l0) * 64 + e];
  }
  for (int e = t; e < 8192; e += 256) {
    int c = e >> 6, d = e & 63;
    m_s[c * 65 + d] = means[e];
  }
  __syncthreads();
  int px = t >> 3, cg = t & 7;
  float best = -1e30f;
  int bidx = 0;
  const float* xr = &x_s[px * 65];
  for (int cc = 0; cc < 16; ++cc) {
    int c = cg + 8 * cc;
    const float* mr = &m_s[c * 65];
    float d = 0.f;
#pragma unroll
    for (int dd = 0; dd < 64; ++dd) d += xr[dd] * mr[dd];
    if (d > best || (d == best && c < bidx)) { best = d; bidx = c; }
  }
  bv_s[px * 8 + cg] = best;
  bi_s[px * 8 + cg] = bidx;
  __syncthreads();
  if (cg == 0) {
    float bb = bv_s[px * 8];
    int bbi = bi_s[px * 8];
    for (int g = 1; g < 8; ++g) {
      float v = bv_s[px * 8 + g];
      int vi = bi_s[px * 8 + g];
      if (v > bb || (v == bb && vi < bbi)) { bb = v; bbi = vi; }
    }
    buckets[b * L + l0 + px] = bbi;
  }
}

// ---------------- K4: parallel stable counting sort ----------------
#define SCH 256
#define CHL 36
__global__ __launch_bounds__(256) void k_sort(const int* __restrict__ buckets,
                                              int* __restrict__ sidx) {
  int b = blockIdx.x, t = threadIdx.x;
  __shared__ int keys_s[L];
  __shared__ unsigned short cnt_s[SCH][130];
  __shared__ int halfsum0[NCLUST];
  __shared__ int keytotal[NCLUST];
  __shared__ int keybase[NCLUST];
  const int* bk = buckets + b * L;
  for (int i = t; i < L; i += SCH) keys_s[i] = bk[i];
  for (int i = 0; i < 130; ++i) cnt_s[t][i] = 0;
  __syncthreads();
  {
    int base = t * CHL;
    for (int i = 0; i < CHL; ++i) cnt_s[t][keys_s[base + i]]++;
  }
  __syncthreads();
  {
    int kkey = t & 127, h = t >> 7;
    int c0 = h * 128;
    int run = 0;
    for (int c = 0; c < 128; ++c) {
      int v = cnt_s[c0 + c][kkey];
      cnt_s[c0 + c][kkey] = (unsigned short)run;
      run += v;
    }
    if (h == 0) halfsum0[kkey] = run;
    else keytotal[kkey] = run;
  }
  __syncthreads();
  if (t < NCLUST) keytotal[t] += halfsum0[t];
  __syncthreads();
  if (t == 0) {
    int s = 0;
    for (int i = 0; i < NCLUST; ++i) { keybase[i] = s; s += keytotal[i]; }
  }
  __syncthreads();
  {
    int h = t >> 7;
    int base = t * CHL;
    int* sb = sidx + b * L;
    for (int i = 0; i < CHL; ++i) {
      int kkey = keys_s[base + i];
      int pos = keybase[kkey] + (h ? halfsum0[kkey] : 0) + cnt_s[t][kkey];
      cnt_s[t][kkey]++;
      sb[pos] = base + i;
    }
  }
}

// ---------------- K5: gather + normalize -> xk (bf16 swizzled), yt (bf16 V^T tiles) ----------------
__global__ __launch_bounds__(256) void k_gather(const float* __restrict__ xe,
                                                const float* __restrict__ ye,
                                                const int* __restrict__ sidx,
                                                unsigned short* __restrict__ xk,
                                                unsigned short* __restrict__ yt,
                                                float* __restrict__ norms) {
  int it = blockIdx.x, b = blockIdx.y;
  int i0 = it * 64;
  __shared__ float x_s[64 * 65];
  __shared__ float y_s[16 * 260];
  __shared__ int idx_s[64];
  __shared__ float scale_s[64];
  int t = threadIdx.x;
  if (t < 64) idx_s[t] = sidx[b * L + i0 + t];
  __syncthreads();
  for (int e = t; e < 4096; e += 256) {
    int i = e >> 6, d = e & 63;
    x_s[i * 65 + d] = xe[((size_t)b * L + idx_s[i]) * 64 + d];
  }
  __syncthreads();
  if (t < 64) {
    float s = 0.f;
    const float* xr = &x_s[t * 65];
#pragma unroll
    for (int d = 0; d < 64; ++d) s += xr[d] * xr[d];
    float n = fmaxf(sqrtf(s), 5e-5f);
    norms[b * L + i0 + t] = n;
    scale_s[t] = 1.0f / n;
  }
  __syncthreads();
  for (int e = t; e < 4096; e += 256) {
    int i = e >> 6, d = e & 63;
    int ig = i0 + i;
    int db = (((d >> 3) ^ (ig & 7)) << 3) | (d & 7);
    xk[((size_t)b * L + ig) * 64 + db] = (unsigned short)f2bf(x_s[i * 65 + d] * scale_s[i]);
  }
  for (int tile = 0; tile < 4; ++tile) {
    for (int e = t; e < 4096; e += 256) {
      int i16 = e >> 8, c = e & 255;
      y_s[i16 * 260 + c] = ye[((size_t)b * L + idx_s[tile * 16 + i16]) * 256 + c];
    }
    __syncthreads();
    size_t tb = (size_t)b * L * 256 + (size_t)((i0 >> 4) + tile) * 4096;
    for (int e = t; e < 4096; e += 256) {
      int c = e >> 4, k16 = e & 15;
      int sw = ((((k16 >> 2) ^ ((c >> 2) & 3)) << 2) | (k16 & 3));
      yt[tb + c * 16 + sw] = (unsigned short)f2bf(y_s[k16 * 260 + c]);
    }
    __syncthreads();
  }
}

// ---------------- K6: flash MFMA attention ----------------
__global__ __launch_bounds__(192, 3) void k_attn(const unsigned short* __restrict__ xk,
                                                 const unsigned short* __restrict__ yt,
                                                 const float* __restrict__ norms,
                                                 const int* __restrict__ sidx,
                                                 float* __restrict__ retb) {
  int qc = blockIdx.x, k = blockIdx.y, b = blockIdx.z;
  __shared__ __align__(16) char lds[40960];
  int t = threadIdx.x;
  int lane = t & 63;
  int g = lane >> 4, kr = lane & 15;
  int kbase = k * WIN;
  int qr0 = kbase + qc * 48 + (t >> 6) * 16;
  int qrow = qr0 + kr;

  s8v qf[2];
#pragma unroll
  for (int s = 0; s < 2; ++s) {
    int blk = (4 * s + g) ^ (qrow & 7);
    qf[s] = *(const s8v*)(xk + ((size_t)b * L + qrow) * 64 + blk * 8);
  }
  float qn = norms[(size_t)b * L + qrow];

  f32x4 acc[16];
#pragma unroll
  for (int nf = 0; nf < 16; ++nf) acc[nf] = (f32x4){0.f, 0.f, 0.f, 0.f};
  float runm = -3e38f, runsum = 0.f;

  auto stage = [&](int c, int buf) {
    char* kb = lds + buf * 20480;
    char* vb = kb + 4096;
    for (int e = t; e < 1280; e += 192) {
      if (e < 256) {
        int key32 = e >> 3;
        if (c == 13 && key32 >= 16) continue;
        int j = c * 32 + key32;
        int r = (j >= 288) ? 2 : (j >= 144) ? 1 : 0;
        int kk = (r == 0) ? k : (r == 1) ? ((k + 63) & 63) : ((k + 1) & 63);
        int phys = kk * WIN + (j - r * 144);
        const char* gp = (const char*)xk + (((size_t)b * L + phys) * 64 + (e & 7) * 8) * 2;
        __builtin_amdgcn_global_load_lds((const __attribute__((address_space(1))) void*)gp,
                                         (__attribute__((address_space(3))) void*)(kb + e * 16),
                                         16, 0, 0);
      } else {
        int u = e - 256;
        int f = u >> 9;
        if (c == 13 && f == 1) continue;
        int j0 = c * 32 + f * 16;
        int r = (j0 >= 288) ? 2 : (j0 >= 144) ? 1 : 0;
        int kk = (r == 0) ? k : (r == 1) ? ((k + 63) & 63) : ((k + 1) & 63);
        int rowbase = kk * WIN + (j0 - r * 144);
        const char* gp = (const char*)yt + ((size_t)b * L + rowbase) * 512 + (size_t)(u & 511) * 16;
        __builtin_amdgcn_global_load_lds((const __attribute__((address_space(1))) void*)gp,
                                         (__attribute__((address_space(3))) void*)(vb + u * 16),
                                         16, 0, 0);
      }
    }
  };

  auto compute = [&](int c, int buf) {
    char* kb = lds + buf * 20480;
    char* vb = kb + 4096;
    int nm = (c == 13) ? 1 : 2;
    f32x4 sa[2];
    sa[0] = (f32x4){0.f, 0.f, 0.f, 0.f};
    sa[1] = (f32x4){0.f, 0.f, 0.f, 0.f};
#pragma unroll
    for (int m = 0; m < 2; ++m)
      if (m < nm) {
        int row32 = m * 16 + kr;
#pragma unroll
        for (int s = 0; s < 2; ++s) {
          int off = row32 * 128 + (((4 * s + g) ^ (row32 & 7)) * 16);
          s8v kf = *(const s8v*)(kb + off);
          sa[m] = __builtin_amdgcn_mfma_f32_16x16x32_bf16(kf, qf[s], sa[m], 0, 0, 0);
        }
      }
    float p[2][4];
    float mx = -3e38f;
#pragma unroll
    for (int m = 0; m < 2; ++m)
#pragma unroll
      for (int r = 0; r < 4; ++r) {
        float v = (m < nm) ? sa[m][r] * qn : -3e38f;
        p[m][r] = v;
        mx = fmaxf(mx, v);
      }
    mx = fmaxf(mx, __shfl_xor(mx, 16));
    mx = fmaxf(mx, __shfl_xor(mx, 32));
    float newm = fmaxf(runm, mx);
    float corr = __expf(runm - newm);
    runm = newm;
    float psum = 0.f;
#pragma unroll
    for (int m = 0; m < 2; ++m)
#pragma unroll
      for (int r = 0; r < 4; ++r) {
        float pv = __expf(p[m][r] - newm);
        p[m][r] = pv;
        psum += pv;
      }
    runsum = runsum * corr + psum;
    if (__any(corr < 1.0f)) {
      float f0 = __shfl(corr, 4 * g + 0);
      float f1 = __shfl(corr, 4 * g + 1);
      float f2 = __shfl(corr, 4 * g + 2);
      float f3 = __shfl(corr, 4 * g + 3);
#pragma unroll
      for (int nf = 0; nf < 16; ++nf) {
        acc[nf][0] *= f0; acc[nf][1] *= f1; acc[nf][2] *= f2; acc[nf][3] *= f3;
      }
    }
    s8v pa;
#pragma unroll
    for (int e2 = 0; e2 < 8; ++e2) pa[e2] = f2bf(p[e2 >> 2][e2 & 3]);
#pragma unroll
    for (int nf = 0; nf < 16; ++nf) {
      int cch = nf * 16 + kr;
      int grp = g ^ ((cch >> 2) & 3);
      s4v lo = *(const s4v*)(vb + cch * 32 + grp * 8);
      s4v hi = *(const s4v*)(vb + 8192 + cch * 32 + grp * 8);
      s8v bfv = __builtin_shufflevector(lo, hi, 0, 1, 2, 3, 4, 5, 6, 7);
      acc[nf] = __builtin_amdgcn_mfma_f32_16x16x32_bf16(pa, bfv, acc[nf], 0, 0, 0);
    }
  };

  stage(0, 0);
  __syncthreads();
  for (int c = 0; c < 14; ++c) {
    if (c < 13) stage(c + 1, (c + 1) & 1);
    compute(c, c & 1);
    __syncthreads();
  }

  runsum += __shfl_xor(runsum, 16);
  runsum += __shfl_xor(runsum, 32);
  float inv = 1.0f / runsum;
  float invr[4];
  int lorig[4];
#pragma unroll
  for (int r = 0; r < 4; ++r) {
    invr[r] = __shfl(inv, 4 * g + r);
    lorig[r] = sidx[b * L + qr0 + 4 * g + r];
  }
#pragma unroll
  for (int nf = 0; nf < 16; ++nf)
#pragma unroll
    for (int r = 0; r < 4; ++r)
      retb[((size_t)b * L + lorig[r]) * 256 + nf * 16 + kr] = acc[nf][r] * invr[r];
}

// ---------------- K7: transpose + residual ----------------
__global__ __launch_bounds__(256) void k_final(const float* __restrict__ in,
                                               const float* __restrict__ retb,
                                               float* __restrict__ out) {
  int lt = blockIdx.x, ct = blockIdx.y, b = blockIdx.z;
  int l0 = lt * 32, c0 = ct * 32;
  __shared__ float t_s[32][33];
  int t = threadIdx.x;
  for (int e = t; e < 1024; e += 256) {
    int i = e >> 5, j = e & 31;
    t_s[i][j] = retb[((size_t)b * L + l0 + i) * 256 + c0 + j];
  }
  __syncthreads();
  for (int e = t; e < 1024; e += 256) {
    int ci = e >> 5, lj = e & 31;
    size_t o = ((size_t)b * CC + c0 + ci) * L + l0 + lj;
    out[o] = in[o] + 0.1f * t_s[lj][ci];
  }
}

extern "C" void kernel_launch(void* const* d_in, const int* in_sizes, int n_in,
                              void* d_out, int out_size, void* d_ws, size_t ws_size,
                              hipStream_t stream) {
  const float* input = (const float*)d_in[0];
  const float* wm = (const float*)d_in[1];
  const float* bm = (const float*)d_in[2];
  const float* wa = (const float*)d_in[3];
  const float* ba = (const float*)d_in[4];
  const float* means = (const float*)d_in[5];
  float* out = (float*)d_out;

  float* ws = (float*)d_ws;
  float* x_embed = ws;                                      // 4,718,592 f
  float* y_embed = ws + 4718592ull;                         // 18,874,368 f (aliased: xpart x3, retb)
  float* retb = y_embed;
  float* xpart = y_embed;                                   // 3 x 4,718,592 f (consumed before conv1)
  unsigned short* xk = (unsigned short*)(ws + 23592960ull); // 4,718,592 bf16
  unsigned short* yt = (unsigned short*)(ws + 25952256ull); // 18,874,368 bf16
  float* norms = ws + 35389440ull;                          // 73,728 f
  int* buckets = (int*)(ws + 35463168ull);                  // 73,728 i
  int* sidx = buckets + 73728;                              // 73,728 i
  float* wt = ws + 23592960ull;                             // aliases xk region (147,456 f)

  k_wprep<<<dim3(576), 256, 0, stream>>>(wm, wt);
  k_conv3<<<dim3(48, 4, 8), 256, 0, stream>>>(input, wt, bm, x_embed, xpart);
  k_xred<<<dim3(4608), 256, 0, stream>>>(x_embed, xpart);
  k_conv1<<<dim3(144, 4, 8), 256, 0, stream>>>(input, wa, ba, y_embed);
  k_bucket<<<dim3(288, 8), 256, 0, stream>>>(x_embed, means, buckets);
  k_sort<<<dim3(8), 256, 0, stream>>>(buckets, sidx);
  k_gather<<<dim3(144, 8), 256, 0, stream>>>(x_embed, y_embed, sidx, xk, yt, norms);
  k_attn<<<dim3(3, 64, 8), 192, 0, stream>>>(xk, yt, norms, sidx, retb);
  k_final<<<dim3(288, 8, 8), 256, 0, stream>>>(input, retb, out);
}

// Round 9
// 750.357 us; speedup vs baseline: 7.6571x; 7.6571x over previous
//
#include <hip/hip_runtime.h>
#include <math.h>

#define L 9216
#define HH 96
#define WW 96
#define CC 256
#define CR 64
#define NCLUST 128
#define WIN 144
#define NK 64   // L/WIN

typedef float f32x4 __attribute__((ext_vector_type(4)));
typedef short s8v __attribute__((ext_vector_type(8)));
typedef short s4v __attribute__((ext_vector_type(4)));

static __device__ __forceinline__ short f2bf(float x) {
  union { float f; unsigned u; } v; v.f = x;
  unsigned r = (v.u + 0x7FFF + ((v.u >> 16) & 1)) >> 16;
  return (short)r;
}

// ---------------- K0: weight transpose wm[oc][ic*9+tap] -> wt[ic*9+tap][oc] ----------------
__global__ __launch_bounds__(256) void k_wprep(const float* __restrict__ wm,
                                               float* __restrict__ wt) {
  int idx = blockIdx.x * 256 + threadIdx.x;
  if (idx < 2304 * 64) {
    int oc = idx & 63, r = idx >> 6;
    wt[r * 64 + oc] = wm[(size_t)oc * 2304 + r];
  }
}

// ---------------- K1: conv3x3 (pad=1), IC split in 2 halves ----------------
// grid (96 rows, 2 ic-halves, 8 b), 128 threads = 16 ocg x 8 colg; tile 4 oc x 12 cols.
// 32 chunks of 4 ic. LDS ~14.6 KB. ich==0 -> x_embed (with bias); ich==1 -> xpart.
// [REVERT: this is the exact version that measured 443 us (R6 bench), VGPR=60, no scratch]
__global__ __launch_bounds__(128) void k_conv3(const float* __restrict__ in,
                                               const float* __restrict__ wt,
                                               const float* __restrict__ bm,
                                               float* __restrict__ xe,
                                               float* __restrict__ xpart) {
  int h = blockIdx.x, ich = blockIdx.y, b = blockIdx.z;
  __shared__ float in_s[4][3][100];   // [ic][row][col], zero-padded halo
  __shared__ float w_s[36][68];       // [ic*9+tap][oc], padded stride
  int t = threadIdx.x;
  int ocg = t & 15, colg = t >> 4;
  int oc0 = ocg * 4, c0 = colg * 12;
  float acc[4][12];
#pragma unroll
  for (int j = 0; j < 4; ++j) {
    float bv = ich ? 0.f : bm[oc0 + j];
#pragma unroll
    for (int i = 0; i < 12; ++i) acc[j][i] = bv;
  }
  const float* inb = in + (size_t)b * CC * L + (size_t)ich * 128 * L;
  const float* wtb = wt + (size_t)ich * 128 * 9 * 64;
#pragma unroll 1
  for (int icc = 0; icc < 32; ++icc) {
    int ic0 = icc * 4;
    // stage input rows h-1..h+1 (4 ics), zeroed borders
    for (int e = t; e < 1200; e += 128) {
      int ic = e / 300, rem = e % 300;
      int r = rem / 100, s = rem % 100;
      int gr = h + r - 1, gc = s - 1;
      float v = 0.f;
      if (gr >= 0 && gr < HH && gc >= 0 && gc < WW)
        v = inb[(size_t)(ic0 + ic) * L + gr * WW + gc];
      in_s[ic][r][s] = v;
    }
    // stage weights: contiguous slab wtb[ic0*9 .. +36)[64]
    for (int e = t; e < 2304; e += 128) {
      int rt = e >> 6, oc = e & 63;
      w_s[rt][oc] = wtb[(size_t)(ic0 * 9 + rt) * 64 + oc];
    }
    __syncthreads();
#pragma unroll
    for (int ic = 0; ic < 4; ++ic) {
#pragma unroll
      for (int kh = 0; kh < 3; ++kh) {
        float ivf[16];
#pragma unroll
        for (int q = 0; q < 4; ++q)
          *(f32x4*)&ivf[q * 4] = *(const f32x4*)&in_s[ic][kh][c0 + q * 4];
#pragma unroll
        for (int kw = 0; kw < 3; ++kw) {
          f32x4 wv = *(const f32x4*)&w_s[ic * 9 + kh * 3 + kw][oc0];
#pragma unroll
          for (int j = 0; j < 4; ++j) {
            float wj = wv[j];
#pragma unroll
            for (int i = 0; i < 12; ++i) acc[j][i] += wj * ivf[i + kw];
          }
        }
      }
    }
    __syncthreads();
  }
  float* dst = ich ? xpart : xe;
  int lbase = h * WW + c0;
#pragma unroll
  for (int i = 0; i < 12; ++i) {
    f32x4 o = {acc[0][i], acc[1][i], acc[2][i], acc[3][i]};
    *(f32x4*)&dst[((size_t)b * L + lbase + i) * CR + oc0] = o;
  }
}

// ---------------- K1b: x_embed += xpart ----------------
__global__ __launch_bounds__(256) void k_xred(float* __restrict__ xe,
                                              const float* __restrict__ xpart) {
  int idx = blockIdx.x * 256 + threadIdx.x;
  if (idx < 1179648) {
    f32x4 a = *(const f32x4*)&xe[idx * 4];
    f32x4 bq = *(const f32x4*)&xpart[idx * 4];
    a += bq;
    *(f32x4*)&xe[idx * 4] = a;
  }
}

// ---------------- K2: conv1x1 -> y_embed[b][l][256] ----------------
// (tweak: stride 66->68 so weight rows are 16B-aligned; one b128 weight read per ic)
__global__ __launch_bounds__(256) void k_conv1(const float* __restrict__ in,
                                               const float* __restrict__ wa,
                                               const float* __restrict__ ba,
                                               float* __restrict__ ye) {
  int lt = blockIdx.x, ot = blockIdx.y, b = blockIdx.z;
  int l0 = lt * 64, ocb = ot * 64;
  __shared__ float in_s[32 * 64];
  __shared__ float w_s[32 * 68];
  int t = threadIdx.x;
  int ocg = t & 15, pg = t >> 4;
  int oc0 = ocg * 4, px0 = pg * 4;
  float acc[4][4];
  for (int p = 0; p < 4; ++p)
    for (int j = 0; j < 4; ++j) acc[p][j] = ba[ocb + oc0 + j];
  const float* inb = in + (size_t)b * CC * L;
  for (int icc = 0; icc < 8; ++icc) {
    int ic0 = icc * 32;
    for (int e = t; e < 2048; e += 256) {
      int ic = e >> 6, px = e & 63;
      in_s[ic * 64 + px] = inb[(size_t)(ic0 + ic) * L + l0 + px];
    }
    for (int e = t; e < 2048; e += 256) {
      int oc = e >> 5, ic = e & 31;
      w_s[ic * 68 + oc] = wa[(size_t)(ocb + oc) * CC + ic0 + ic];
    }
    __syncthreads();
    for (int ic = 0; ic < 32; ++ic) {
      f32x4 wv = *(const f32x4*)&w_s[ic * 68 + oc0];
      float4 xv = *(float4*)&in_s[ic * 64 + px0];
      acc[0][0] += xv.x * wv[0]; acc[0][1] += xv.x * wv[1]; acc[0][2] += xv.x * wv[2]; acc[0][3] += xv.x * wv[3];
      acc[1][0] += xv.y * wv[0]; acc[1][1] += xv.y * wv[1]; acc[1][2] += xv.y * wv[2]; acc[1][3] += xv.y * wv[3];
      acc[2][0] += xv.z * wv[0]; acc[2][1] += xv.z * wv[1]; acc[2][2] += xv.z * wv[2]; acc[2][3] += xv.z * wv[3];
      acc[3][0] += xv.w * wv[0]; acc[3][1] += xv.w * wv[1]; acc[3][2] += xv.w * wv[2]; acc[3][3] += xv.w * wv[3];
    }
    __syncthreads();
  }
  for (int p = 0; p < 4; ++p) {
    float4 o;
    o.x = acc[p][0]; o.y = acc[p][1]; o.z = acc[p][2]; o.w = acc[p][3];
    *(float4*)&ye[((size_t)b * L + l0 + px0 + p) * CC + ocb + oc0] = o;
  }
}

// ---------------- K3: buckets = argmax_c(x . mean_c) ----------------
__global__ __launch_bounds__(256) void k_bucket(const float* __restrict__ xe,
                                                const float* __restrict__ means,
                                                int* __restrict__ buckets) {
  int lt = blockIdx.x, b = blockIdx.y;
  int l0 = lt * 32;
  __shared__ float x_s[32 * 65];
  __shared__ float m_s[128 * 65];
  __shared__ float bv_s[32 * 8];
  __shared__ int bi_s[32 * 8];
  int t = threadIdx.x;
  for (int e = t; e < 2048; e += 256) {
    int px = e >> 6, d = e & 63;
    x_s[px * 65 + d] = xe[((size_t)b * L + l0) * 64 + e];
  }
  for (int e = t; e < 8192; e += 256) {
    int c = e >> 6, d = e & 63;
    m_s[c * 65 + d] = means[e];
  }
  __syncthreads();
  int px = t >> 3, cg = t & 7;
  float best = -1e30f;
  int bidx = 0;
  const float* xr = &x_s[px * 65];
  for (int cc = 0; cc < 16; ++cc) {
    int c = cg + 8 * cc;
    const float* mr = &m_s[c * 65];
    float d = 0.f;
#pragma unroll
    for (int dd = 0; dd < 64; ++dd) d += xr[dd] * mr[dd];
    if (d > best || (d == best && c < bidx)) { best = d; bidx = c; }
  }
  bv_s[px * 8 + cg] = best;
  bi_s[px * 8 + cg] = bidx;
  __syncthreads();
  if (cg == 0) {
    float bb = bv_s[px * 8];
    int bbi = bi_s[px * 8];
    for (int g = 1; g < 8; ++g) {
      float v = bv_s[px * 8 + g];
      int vi = bi_s[px * 8 + g];
      if (v > bb || (v == bb && vi < bbi)) { bb = v; bbi = vi; }
    }
    buckets[b * L + l0 + px] = bbi;
  }
}

// ---------------- K4: parallel stable counting sort ----------------
#define SCH 256
#define CHL 36
__global__ __launch_bounds__(256) void k_sort(const int* __restrict__ buckets,
                                              int* __restrict__ sidx) {
  int b = blockIdx.x, t = threadIdx.x;
  __shared__ int keys_s[L];
  __shared__ unsigned short cnt_s[SCH][130];
  __shared__ int halfsum0[NCLUST];
  __shared__ int keytotal[NCLUST];
  __shared__ int keybase[NCLUST];
  const int* bk = buckets + b * L;
  for (int i = t; i < L; i += SCH) keys_s[i] = bk[i];
  for (int i = 0; i < 130; ++i) cnt_s[t][i] = 0;
  __syncthreads();
  {
    int base = t * CHL;
    for (int i = 0; i < CHL; ++i) cnt_s[t][keys_s[base + i]]++;
  }
  __syncthreads();
  {
    int kkey = t & 127, h = t >> 7;
    int c0 = h * 128;
    int run = 0;
    for (int c = 0; c < 128; ++c) {
      int v = cnt_s[c0 + c][kkey];
      cnt_s[c0 + c][kkey] = (unsigned short)run;
      run += v;
    }
    if (h == 0) halfsum0[kkey] = run;
    else keytotal[kkey] = run;
  }
  __syncthreads();
  if (t < NCLUST) keytotal[t] += halfsum0[t];
  __syncthreads();
  if (t == 0) {
    int s = 0;
    for (int i = 0; i < NCLUST; ++i) { keybase[i] = s; s += keytotal[i]; }
  }
  __syncthreads();
  {
    int h = t >> 7;
    int base = t * CHL;
    int* sb = sidx + b * L;
    for (int i = 0; i < CHL; ++i) {
      int kkey = keys_s[base + i];
      int pos = keybase[kkey] + (h ? halfsum0[kkey] : 0) + cnt_s[t][kkey];
      cnt_s[t][kkey]++;
      sb[pos] = base + i;
    }
  }
}

// ---------------- K5: gather + normalize -> xk (bf16 swizzled), yt (bf16 V^T tiles) ----------------
__global__ __launch_bounds__(256) void k_gather(const float* __restrict__ xe,
                                                const float* __restrict__ ye,
                                                const int* __restrict__ sidx,
                                                unsigned short* __restrict__ xk,
                                                unsigned short* __restrict__ yt,
                                                float* __restrict__ norms) {
  int it = blockIdx.x, b = blockIdx.y;
  int i0 = it * 64;
  __shared__ float x_s[64 * 65];
  __shared__ float y_s[16 * 260];
  __shared__ int idx_s[64];
  __shared__ float scale_s[64];
  int t = threadIdx.x;
  if (t < 64) idx_s[t] = sidx[b * L + i0 + t];
  __syncthreads();
  for (int e = t; e < 4096; e += 256) {
    int i = e >> 6, d = e & 63;
    x_s[i * 65 + d] = xe[((size_t)b * L + idx_s[i]) * 64 + d];
  }
  __syncthreads();
  if (t < 64) {
    float s = 0.f;
    const float* xr = &x_s[t * 65];
#pragma unroll
    for (int d = 0; d < 64; ++d) s += xr[d] * xr[d];
    float n = fmaxf(sqrtf(s), 5e-5f);
    norms[b * L + i0 + t] = n;
    scale_s[t] = 1.0f / n;
  }
  __syncthreads();
  for (int e = t; e < 4096; e += 256) {
    int i = e >> 6, d = e & 63;
    int ig = i0 + i;
    int db = (((d >> 3) ^ (ig & 7)) << 3) | (d & 7);
    xk[((size_t)b * L + ig) * 64 + db] = (unsigned short)f2bf(x_s[i * 65 + d] * scale_s[i]);
  }
  for (int tile = 0; tile < 4; ++tile) {
    for (int e = t; e < 4096; e += 256) {
      int i16 = e >> 8, c = e & 255;
      y_s[i16 * 260 + c] = ye[((size_t)b * L + idx_s[tile * 16 + i16]) * 256 + c];
    }
    __syncthreads();
    size_t tb = (size_t)b * L * 256 + (size_t)((i0 >> 4) + tile) * 4096;
    for (int e = t; e < 4096; e += 256) {
      int c = e >> 4, k16 = e & 15;
      int sw = ((((k16 >> 2) ^ ((c >> 2) & 3)) << 2) | (k16 & 3));
      yt[tb + c * 16 + sw] = (unsigned short)f2bf(y_s[k16 * 260 + c]);
    }
    __syncthreads();
  }
}

// ---------------- K6: flash MFMA attention ----------------
__global__ __launch_bounds__(192, 3) void k_attn(const unsigned short* __restrict__ xk,
                                                 const unsigned short* __restrict__ yt,
                                                 const float* __restrict__ norms,
                                                 const int* __restrict__ sidx,
                                                 float* __restrict__ retb) {
  int qc = blockIdx.x, k = blockIdx.y, b = blockIdx.z;
  __shared__ __align__(16) char lds[40960];
  int t = threadIdx.x;
  int lane = t & 63;
  int g = lane >> 4, kr = lane & 15;
  int kbase = k * WIN;
  int qr0 = kbase + qc * 48 + (t >> 6) * 16;
  int qrow = qr0 + kr;

  s8v qf[2];
#pragma unroll
  for (int s = 0; s < 2; ++s) {
    int blk = (4 * s + g) ^ (qrow & 7);
    qf[s] = *(const s8v*)(xk + ((size_t)b * L + qrow) * 64 + blk * 8);
  }
  float qn = norms[(size_t)b * L + qrow];

  f32x4 acc[16];
#pragma unroll
  for (int nf = 0; nf < 16; ++nf) acc[nf] = (f32x4){0.f, 0.f, 0.f, 0.f};
  float runm = -3e38f, runsum = 0.f;

  auto stage = [&](int c, int buf) {
    char* kb = lds + buf * 20480;
    char* vb = kb + 4096;
    for (int e = t; e < 1280; e += 192) {
      if (e < 256) {
        int key32 = e >> 3;
        if (c == 13 && key32 >= 16) continue;
        int j = c * 32 + key32;
        int r = (j >= 288) ? 2 : (j >= 144) ? 1 : 0;
        int kk = (r == 0) ? k : (r == 1) ? ((k + 63) & 63) : ((k + 1) & 63);
        int phys = kk * WIN + (j - r * 144);
        const char* gp = (const char*)xk + (((size_t)b * L + phys) * 64 + (e & 7) * 8) * 2;
        __builtin_amdgcn_global_load_lds((const __attribute__((address_space(1))) void*)gp,
                                         (__attribute__((address_space(3))) void*)(kb + e * 16),
                                         16, 0, 0);
      } else {
        int u = e - 256;
        int f = u >> 9;
        if (c == 13 && f == 1) continue;
        int j0 = c * 32 + f * 16;
        int r = (j0 >= 288) ? 2 : (j0 >= 144) ? 1 : 0;
        int kk = (r == 0) ? k : (r == 1) ? ((k + 63) & 63) : ((k + 1) & 63);
        int rowbase = kk * WIN + (j0 - r * 144);
        const char* gp = (const char*)yt + ((size_t)b * L + rowbase) * 512 + (size_t)(u & 511) * 16;
        __builtin_amdgcn_global_load_lds((const __attribute__((address_space(1))) void*)gp,
                                         (__attribute__((address_space(3))) void*)(vb + u * 16),
                                         16, 0, 0);
      }
    }
  };

  auto compute = [&](int c, int buf) {
    char* kb = lds + buf * 20480;
    char* vb = kb + 4096;
    int nm = (c == 13) ? 1 : 2;
    f32x4 sa[2];
    sa[0] = (f32x4){0.f, 0.f, 0.f, 0.f};
    sa[1] = (f32x4){0.f, 0.f, 0.f, 0.f};
#pragma unroll
    for (int m = 0; m < 2; ++m)
      if (m < nm) {
        int row32 = m * 16 + kr;
#pragma unroll
        for (int s = 0; s < 2; ++s) {
          int off = row32 * 128 + (((4 * s + g) ^ (row32 & 7)) * 16);
          s8v kf = *(const s8v*)(kb + off);
          sa[m] = __builtin_amdgcn_mfma_f32_16x16x32_bf16(kf, qf[s], sa[m], 0, 0, 0);
        }
      }
    float p[2][4];
    float mx = -3e38f;
#pragma unroll
    for (int m = 0; m < 2; ++m)
#pragma unroll
      for (int r = 0; r < 4; ++r) {
        float v = (m < nm) ? sa[m][r] * qn : -3e38f;
        p[m][r] = v;
        mx = fmaxf(mx, v);
      }
    mx = fmaxf(mx, __shfl_xor(mx, 16));
    mx = fmaxf(mx, __shfl_xor(mx, 32));
    float newm = fmaxf(runm, mx);
    float corr = __expf(runm - newm);
    runm = newm;
    float psum = 0.f;
#pragma unroll
    for (int m = 0; m < 2; ++m)
#pragma unroll
      for (int r = 0; r < 4; ++r) {
        float pv = __expf(p[m][r] - newm);
        p[m][r] = pv;
        psum += pv;
      }
    runsum = runsum * corr + psum;
    if (__any(corr < 1.0f)) {
      float f0 = __shfl(corr, 4 * g + 0);
      float f1 = __shfl(corr, 4 * g + 1);
      float f2 = __shfl(corr, 4 * g + 2);
      float f3 = __shfl(corr, 4 * g + 3);
#pragma unroll
      for (int nf = 0; nf < 16; ++nf) {
        acc[nf][0] *= f0; acc[nf][1] *= f1; acc[nf][2] *= f2; acc[nf][3] *= f3;
      }
    }
    s8v pa;
#pragma unroll
    for (int e2 = 0; e2 < 8; ++e2) pa[e2] = f2bf(p[e2 >> 2][e2 & 3]);
#pragma unroll
    for (int nf = 0; nf < 16; ++nf) {
      int cch = nf * 16 + kr;
      int grp = g ^ ((cch >> 2) & 3);
      s4v lo = *(const s4v*)(vb + cch * 32 + grp * 8);
      s4v hi = *(const s4v*)(vb + 8192 + cch * 32 + grp * 8);
      s8v bfv = __builtin_shufflevector(lo, hi, 0, 1, 2, 3, 4, 5, 6, 7);
      acc[nf] = __builtin_amdgcn_mfma_f32_16x16x32_bf16(pa, bfv, acc[nf], 0, 0, 0);
    }
  };

  stage(0, 0);
  __syncthreads();
  for (int c = 0; c < 14; ++c) {
    if (c < 13) stage(c + 1, (c + 1) & 1);
    compute(c, c & 1);
    __syncthreads();
  }

  runsum += __shfl_xor(runsum, 16);
  runsum += __shfl_xor(runsum, 32);
  float inv = 1.0f / runsum;
  float invr[4];
  int lorig[4];
#pragma unroll
  for (int r = 0; r < 4; ++r) {
    invr[r] = __shfl(inv, 4 * g + r);
    lorig[r] = sidx[b * L + qr0 + 4 * g + r];
  }
#pragma unroll
  for (int nf = 0; nf < 16; ++nf)
#pragma unroll
    for (int r = 0; r < 4; ++r)
      retb[((size_t)b * L + lorig[r]) * 256 + nf * 16 + kr] = acc[nf][r] * invr[r];
}

// ---------------- K7: transpose + residual ----------------
__global__ __launch_bounds__(256) void k_final(const float* __restrict__ in,
                                               const float* __restrict__ retb,
                                               float* __restrict__ out) {
  int lt = blockIdx.x, ct = blockIdx.y, b = blockIdx.z;
  int l0 = lt * 32, c0 = ct * 32;
  __shared__ float t_s[32][33];
  int t = threadIdx.x;
  for (int e = t; e < 1024; e += 256) {
    int i = e >> 5, j = e & 31;
    t_s[i][j] = retb[((size_t)b * L + l0 + i) * 256 + c0 + j];
  }
  __syncthreads();
  for (int e = t; e < 1024; e += 256) {
    int ci = e >> 5, lj = e & 31;
    size_t o = ((size_t)b * CC + c0 + ci) * L + l0 + lj;
    out[o] = in[o] + 0.1f * t_s[lj][ci];
  }
}

extern "C" void kernel_launch(void* const* d_in, const int* in_sizes, int n_in,
                              void* d_out, int out_size, void* d_ws, size_t ws_size,
                              hipStream_t stream) {
  const float* input = (const float*)d_in[0];
  const float* wm = (const float*)d_in[1];
  const float* bm = (const float*)d_in[2];
  const float* wa = (const float*)d_in[3];
  const float* ba = (const float*)d_in[4];
  const float* means = (const float*)d_in[5];
  float* out = (float*)d_out;

  float* ws = (float*)d_ws;
  float* x_embed = ws;                                      // 4,718,592 f
  float* y_embed = ws + 4718592ull;                         // 18,874,368 f (aliased as retb)
  float* retb = y_embed;
  unsigned short* xk = (unsigned short*)(ws + 23592960ull); // 4,718,592 bf16
  unsigned short* yt = (unsigned short*)(ws + 25952256ull); // 18,874,368 bf16
  float* norms = ws + 35389440ull;                          // 73,728 f
  int* buckets = (int*)(ws + 35463168ull);                  // 73,728 i
  int* sidx = buckets + 73728;                              // 73,728 i
  float* wt = ws + 23592960ull;                             // aliases xk region (147,456 f)
  float* xpart = ws + 25952256ull;                          // aliases yt region (4,718,592 f)

  k_wprep<<<dim3(576), 256, 0, stream>>>(wm, wt);
  k_conv3<<<dim3(96, 2, 8), 128, 0, stream>>>(input, wt, bm, x_embed, xpart);
  k_xred<<<dim3(4608), 256, 0, stream>>>(x_embed, xpart);
  k_conv1<<<dim3(144, 4, 8), 256, 0, stream>>>(input, wa, ba, y_embed);
  k_bucket<<<dim3(288, 8), 256, 0, stream>>>(x_embed, means, buckets);
  k_sort<<<dim3(8), 256, 0, stream>>>(buckets, sidx);
  k_gather<<<dim3(144, 8), 256, 0, stream>>>(x_embed, y_embed, sidx, xk, yt, norms);
  k_attn<<<dim3(3, 64, 8), 192, 0, stream>>>(xk, yt, norms, sidx, retb);
  k_final<<<dim3(288, 8, 8), 256, 0, stream>>>(input, retb, out);
}

// Round 10
// 451.563 us; speedup vs baseline: 12.7237x; 1.6617x over previous
//
#include <hip/hip_runtime.h>
#include <math.h>

#define L 9216
#define HH 96
#define WW 96
#define CC 256
#define CR 64
#define NCLUST 128
#define WIN 144
#define NK 64   // L/WIN

typedef float f32x4 __attribute__((ext_vector_type(4)));
typedef float f32x16 __attribute__((ext_vector_type(16)));
typedef short s8v __attribute__((ext_vector_type(8)));
typedef short s4v __attribute__((ext_vector_type(4)));

static __device__ __forceinline__ short f2bf(float x) {
  union { float f; unsigned u; } v; v.f = x;
  unsigned r = (v.u + 0x7FFF + ((v.u >> 16) & 1)) >> 16;
  return (short)r;
}
static __device__ __forceinline__ float bf2f(short h) {
  union { float f; unsigned u; } v;
  v.u = ((unsigned)(unsigned short)h) << 16;
  return v.f;
}

// ---------------- K0a: input split fp32 -> xhi/xlo bf16, layout [b][h][icc16][w96][ic16] ----------------
__global__ __launch_bounds__(256) void k_isplit(const float* __restrict__ in,
                                                unsigned short* __restrict__ xhi,
                                                unsigned short* __restrict__ xlo) {
  int h = blockIdx.x, icc = blockIdx.y, b = blockIdx.z;
  __shared__ float tile[16][97];
  int t = threadIdx.x;
  for (int e = t; e < 1536; e += 256) {
    int ic = e / 96, w = e % 96;
    tile[ic][w] = in[((size_t)(b * 256 + icc * 16 + ic)) * L + h * 96 + w];
  }
  __syncthreads();
  size_t base = (((size_t)b * 96 + h) * 16 + icc) * 1536;
  for (int e = t; e < 1536; e += 256) {
    int w = e >> 4, ic = e & 15;
    float v = tile[ic][w];
    short hi = f2bf(v);
    float rv = v - bf2f(hi);
    short lo = f2bf(rv);
    xhi[base + e] = (unsigned short)hi;
    xlo[base + e] = (unsigned short)lo;
  }
}

// ---------------- K0b: weight split -> whiB/wloB [icc][tap][oc64][ic16] bf16 ----------------
__global__ __launch_bounds__(256) void k_wsplit(const float* __restrict__ wm,
                                                unsigned short* __restrict__ whiB,
                                                unsigned short* __restrict__ wloB) {
  int idx = blockIdx.x * 256 + threadIdx.x;
  if (idx < 147456) {
    int ic = idx & 15;
    int oc = (idx >> 4) & 63;
    int g = idx >> 10;
    int tap = g % 9, icc = g / 9;
    float v = wm[(size_t)oc * 2304 + (icc * 16 + ic) * 9 + tap];
    short hi = f2bf(v);
    float rv = v - bf2f(hi);
    whiB[idx] = (unsigned short)hi;
    wloB[idx] = (unsigned short)f2bf(rv);
  }
}

// ---------------- K1: conv3x3 via MFMA (split-bf16, 3 products) ----------------
// grid (96 rows, 8 b), 384 thr = 6 waves; wave = (pt 0..2 [32 pixels], ot 0..1 [32 oc]).
// LDS: input only, [buf][split][row3][col98][ic16] bf16; weights streamed from global (L2).
__global__ __launch_bounds__(384) void k_conv3(const unsigned short* __restrict__ xhi,
                                               const unsigned short* __restrict__ xlo,
                                               const unsigned short* __restrict__ whiB,
                                               const unsigned short* __restrict__ wloB,
                                               const float* __restrict__ bm,
                                               float* __restrict__ xe) {
  int h = blockIdx.x, b = blockIdx.y;
  __shared__ __align__(16) unsigned short lds[2 * 2 * 3 * 98 * 16];  // 37632 B
  int t = threadIdx.x;
  int wave = t >> 6, lane = t & 63;
  int pt = wave % 3, ot = wave / 3;
  int hh = lane >> 5, j = lane & 31;
  int r = lane & 31;

  // zero the halo column slots (0 and 97) of all 2x2x3 planes
  if (t < 384) {
    int slot = t >> 4, ic = t & 15;
    int bs = slot / 6, rem = slot % 6;
    int rr = rem >> 1, cc = rem & 1;
    lds[bs * 4704 + rr * 1568 + (cc ? 97 : 0) * 16 + ic] = 0;
  }

  f32x16 acc = {};

  auto stage = [&](int icc, int buf) {
#pragma unroll
    for (int k3 = 0; k3 < 3; ++k3) {
      int u = t + k3 * 384;
      int s = u / 576;
      int rem = u - s * 576;
      int rr = rem / 192;
      int q = rem - rr * 192;
      int gr = h - 1 + rr;
      unsigned short* dst = &lds[(buf * 2 + s) * 4704 + rr * 1568 + 16 + q * 8];
      if (gr >= 0 && gr < 96) {
        const unsigned short* src =
            (s ? xlo : xhi) + ((((size_t)b * 96 + gr) * 16 + icc) * 1536 + q * 8);
        __builtin_amdgcn_global_load_lds((const __attribute__((address_space(1))) void*)src,
                                         (__attribute__((address_space(3))) void*)dst, 16, 0, 0);
      } else {
        *(s8v*)dst = (s8v){0, 0, 0, 0, 0, 0, 0, 0};
      }
    }
  };

  auto compute = [&](int icc, int buf) {
    const unsigned short* lbase = lds + buf * 9408;
    const unsigned short* wb = whiB + (size_t)icc * 9216;  // 9 taps * 1024
    const unsigned short* wl = wloB + (size_t)icc * 9216;
#pragma unroll
    for (int kh = 0; kh < 3; ++kh)
#pragma unroll
      for (int kw = 0; kw < 3; ++kw) {
        int tap = kh * 3 + kw;
        int aidx = kh * 1568 + (pt * 32 + r + kw) * 16 + hh * 8;
        s8v a_hi = *(const s8v*)(lbase + aidx);
        s8v a_lo = *(const s8v*)(lbase + 4704 + aidx);
        int woff = tap * 1024 + (ot * 32 + j) * 16 + hh * 8;
        s8v b_hi = *(const s8v*)(wb + woff);
        s8v b_lo = *(const s8v*)(wl + woff);
        acc = __builtin_amdgcn_mfma_f32_32x32x16_bf16(a_hi, b_hi, acc, 0, 0, 0);
        acc = __builtin_amdgcn_mfma_f32_32x32x16_bf16(a_hi, b_lo, acc, 0, 0, 0);
        acc = __builtin_amdgcn_mfma_f32_32x32x16_bf16(a_lo, b_hi, acc, 0, 0, 0);
      }
  };

  stage(0, 0);
  __syncthreads();
#pragma unroll 1
  for (int icc = 0; icc < 16; ++icc) {
    int buf = icc & 1;
    if (icc < 15) stage(icc + 1, buf ^ 1);
    compute(icc, buf);
    __syncthreads();
  }

  float bv = bm[ot * 32 + j];
#pragma unroll
  for (int reg = 0; reg < 16; ++reg) {
    int prow = (reg & 3) + 8 * (reg >> 2) + 4 * hh;
    xe[((size_t)b * L + h * 96 + pt * 32 + prow) * 64 + ot * 32 + j] = acc[reg] + bv;
  }
}

// ---------------- K2: conv1x1 -> y_embed[b][l][256] ----------------
__global__ __launch_bounds__(256) void k_conv1(const float* __restrict__ in,
                                               const float* __restrict__ wa,
                                               const float* __restrict__ ba,
                                               float* __restrict__ ye) {
  int lt = blockIdx.x, ot = blockIdx.y, b = blockIdx.z;
  int l0 = lt * 64, ocb = ot * 64;
  __shared__ float in_s[32 * 64];
  __shared__ float w_s[32 * 68];
  int t = threadIdx.x;
  int ocg = t & 15, pg = t >> 4;
  int oc0 = ocg * 4, px0 = pg * 4;
  float acc[4][4];
  for (int p = 0; p < 4; ++p)
    for (int j = 0; j < 4; ++j) acc[p][j] = ba[ocb + oc0 + j];
  const float* inb = in + (size_t)b * CC * L;
  for (int icc = 0; icc < 8; ++icc) {
    int ic0 = icc * 32;
    for (int e = t; e < 2048; e += 256) {
      int ic = e >> 6, px = e & 63;
      in_s[ic * 64 + px] = inb[(size_t)(ic0 + ic) * L + l0 + px];
    }
    for (int e = t; e < 2048; e += 256) {
      int oc = e >> 5, ic = e & 31;
      w_s[ic * 68 + oc] = wa[(size_t)(ocb + oc) * CC + ic0 + ic];
    }
    __syncthreads();
    for (int ic = 0; ic < 32; ++ic) {
      f32x4 wv = *(const f32x4*)&w_s[ic * 68 + oc0];
      float4 xv = *(float4*)&in_s[ic * 64 + px0];
      acc[0][0] += xv.x * wv[0]; acc[0][1] += xv.x * wv[1]; acc[0][2] += xv.x * wv[2]; acc[0][3] += xv.x * wv[3];
      acc[1][0] += xv.y * wv[0]; acc[1][1] += xv.y * wv[1]; acc[1][2] += xv.y * wv[2]; acc[1][3] += xv.y * wv[3];
      acc[2][0] += xv.z * wv[0]; acc[2][1] += xv.z * wv[1]; acc[2][2] += xv.z * wv[2]; acc[2][3] += xv.z * wv[3];
      acc[3][0] += xv.w * wv[0]; acc[3][1] += xv.w * wv[1]; acc[3][2] += xv.w * wv[2]; acc[3][3] += xv.w * wv[3];
    }
    __syncthreads();
  }
  for (int p = 0; p < 4; ++p) {
    float4 o;
    o.x = acc[p][0]; o.y = acc[p][1]; o.z = acc[p][2]; o.w = acc[p][3];
    *(float4*)&ye[((size_t)b * L + l0 + px0 + p) * CC + ocb + oc0] = o;
  }
}

// ---------------- K3: buckets = argmax_c(x . mean_c) ----------------
__global__ __launch_bounds__(256) void k_bucket(const float* __restrict__ xe,
                                                const float* __restrict__ means,
                                                int* __restrict__ buckets) {
  int lt = blockIdx.x, b = blockIdx.y;
  int l0 = lt * 32;
  __shared__ float x_s[32 * 65];
  __shared__ float m_s[128 * 65];
  __shared__ float bv_s[32 * 8];
  __shared__ int bi_s[32 * 8];
  int t = threadIdx.x;
  for (int e = t; e < 2048; e += 256) {
    int px = e >> 6, d = e & 63;
    x_s[px * 65 + d] = xe[((size_t)b * L + l0) * 64 + e];
  }
  for (int e = t; e < 8192; e += 256) {
    int c = e >> 6, d = e & 63;
    m_s[c * 65 + d] = means[e];
  }
  __syncthreads();
  int px = t >> 3, cg = t & 7;
  float best = -1e30f;
  int bidx = 0;
  const float* xr = &x_s[px * 65];
  for (int cc = 0; cc < 16; ++cc) {
    int c = cg + 8 * cc;
    const float* mr = &m_s[c * 65];
    float d = 0.f;
#pragma unroll
    for (int dd = 0; dd < 64; ++dd) d += xr[dd] * mr[dd];
    if (d > best || (d == best && c < bidx)) { best = d; bidx = c; }
  }
  bv_s[px * 8 + cg] = best;
  bi_s[px * 8 + cg] = bidx;
  __syncthreads();
  if (cg == 0) {
    float bb = bv_s[px * 8];
    int bbi = bi_s[px * 8];
    for (int g = 1; g < 8; ++g) {
      float v = bv_s[px * 8 + g];
      int vi = bi_s[px * 8 + g];
      if (v > bb || (v == bb && vi < bbi)) { bb = v; bbi = vi; }
    }
    buckets[b * L + l0 + px] = bbi;
  }
}

// ---------------- K4: parallel stable counting sort ----------------
#define SCH 256
#define CHL 36
__global__ __launch_bounds__(256) void k_sort(const int* __restrict__ buckets,
                                              int* __restrict__ sidx) {
  int b = blockIdx.x, t = threadIdx.x;
  __shared__ int keys_s[L];
  __shared__ unsigned short cnt_s[SCH][130];
  __shared__ int halfsum0[NCLUST];
  __shared__ int keytotal[NCLUST];
  __shared__ int keybase[NCLUST];
  const int* bk = buckets + b * L;
  for (int i = t; i < L; i += SCH) keys_s[i] = bk[i];
  for (int i = 0; i < 130; ++i) cnt_s[t][i] = 0;
  __syncthreads();
  {
    int base = t * CHL;
    for (int i = 0; i < CHL; ++i) cnt_s[t][keys_s[base + i]]++;
  }
  __syncthreads();
  {
    int kkey = t & 127, h = t >> 7;
    int c0 = h * 128;
    int run = 0;
    for (int c = 0; c < 128; ++c) {
      int v = cnt_s[c0 + c][kkey];
      cnt_s[c0 + c][kkey] = (unsigned short)run;
      run += v;
    }
    if (h == 0) halfsum0[kkey] = run;
    else keytotal[kkey] = run;
  }
  __syncthreads();
  if (t < NCLUST) keytotal[t] += halfsum0[t];
  __syncthreads();
  if (t == 0) {
    int s = 0;
    for (int i = 0; i < NCLUST; ++i) { keybase[i] = s; s += keytotal[i]; }
  }
  __syncthreads();
  {
    int h = t >> 7;
    int base = t * CHL;
    int* sb = sidx + b * L;
    for (int i = 0; i < CHL; ++i) {
      int kkey = keys_s[base + i];
      int pos = keybase[kkey] + (h ? halfsum0[kkey] : 0) + cnt_s[t][kkey];
      cnt_s[t][kkey]++;
      sb[pos] = base + i;
    }
  }
}

// ---------------- K5: gather + normalize -> xk (bf16 swizzled), yt (bf16 V^T tiles) ----------------
__global__ __launch_bounds__(256) void k_gather(const float* __restrict__ xe,
                                                const float* __restrict__ ye,
                                                const int* __restrict__ sidx,
                                                unsigned short* __restrict__ xk,
                                                unsigned short* __restrict__ yt,
                                                float* __restrict__ norms) {
  int it = blockIdx.x, b = blockIdx.y;
  int i0 = it * 64;
  __shared__ float x_s[64 * 65];
  __shared__ float y_s[16 * 260];
  __shared__ int idx_s[64];
  __shared__ float scale_s[64];
  int t = threadIdx.x;
  if (t < 64) idx_s[t] = sidx[b * L + i0 + t];
  __syncthreads();
  for (int e = t; e < 4096; e += 256) {
    int i = e >> 6, d = e & 63;
    x_s[i * 65 + d] = xe[((size_t)b * L + idx_s[i]) * 64 + d];
  }
  __syncthreads();
  if (t < 64) {
    float s = 0.f;
    const float* xr = &x_s[t * 65];
#pragma unroll
    for (int d = 0; d < 64; ++d) s += xr[d] * xr[d];
    float n = fmaxf(sqrtf(s), 5e-5f);
    norms[b * L + i0 + t] = n;
    scale_s[t] = 1.0f / n;
  }
  __syncthreads();
  for (int e = t; e < 4096; e += 256) {
    int i = e >> 6, d = e & 63;
    int ig = i0 + i;
    int db = (((d >> 3) ^ (ig & 7)) << 3) | (d & 7);
    xk[((size_t)b * L + ig) * 64 + db] = (unsigned short)f2bf(x_s[i * 65 + d] * scale_s[i]);
  }
  for (int tile = 0; tile < 4; ++tile) {
    for (int e = t; e < 4096; e += 256) {
      int i16 = e >> 8, c = e & 255;
      y_s[i16 * 260 + c] = ye[((size_t)b * L + idx_s[tile * 16 + i16]) * 256 + c];
    }
    __syncthreads();
    size_t tb = (size_t)b * L * 256 + (size_t)((i0 >> 4) + tile) * 4096;
    for (int e = t; e < 4096; e += 256) {
      int c = e >> 4, k16 = e & 15;
      int sw = ((((k16 >> 2) ^ ((c >> 2) & 3)) << 2) | (k16 & 3));
      yt[tb + c * 16 + sw] = (unsigned short)f2bf(y_s[k16 * 260 + c]);
    }
    __syncthreads();
  }
}

// ---------------- K6: flash MFMA attention ----------------
__global__ __launch_bounds__(192, 3) void k_attn(const unsigned short* __restrict__ xk,
                                                 const unsigned short* __restrict__ yt,
                                                 const float* __restrict__ norms,
                                                 const int* __restrict__ sidx,
                                                 float* __restrict__ retb) {
  int qc = blockIdx.x, k = blockIdx.y, b = blockIdx.z;
  __shared__ __align__(16) char lds[40960];
  int t = threadIdx.x;
  int lane = t & 63;
  int g = lane >> 4, kr = lane & 15;
  int kbase = k * WIN;
  int qr0 = kbase + qc * 48 + (t >> 6) * 16;
  int qrow = qr0 + kr;

  s8v qf[2];
#pragma unroll
  for (int s = 0; s < 2; ++s) {
    int blk = (4 * s + g) ^ (qrow & 7);
    qf[s] = *(const s8v*)(xk + ((size_t)b * L + qrow) * 64 + blk * 8);
  }
  float qn = norms[(size_t)b * L + qrow];

  f32x4 acc[16];
#pragma unroll
  for (int nf = 0; nf < 16; ++nf) acc[nf] = (f32x4){0.f, 0.f, 0.f, 0.f};
  float runm = -3e38f, runsum = 0.f;

  auto stage = [&](int c, int buf) {
    char* kb = lds + buf * 20480;
    char* vb = kb + 4096;
    for (int e = t; e < 1280; e += 192) {
      if (e < 256) {
        int key32 = e >> 3;
        if (c == 13 && key32 >= 16) continue;
        int j = c * 32 + key32;
        int r = (j >= 288) ? 2 : (j >= 144) ? 1 : 0;
        int kk = (r == 0) ? k : (r == 1) ? ((k + 63) & 63) : ((k + 1) & 63);
        int phys = kk * WIN + (j - r * 144);
        const char* gp = (const char*)xk + (((size_t)b * L + phys) * 64 + (e & 7) * 8) * 2;
        __builtin_amdgcn_global_load_lds((const __attribute__((address_space(1))) void*)gp,
                                         (__attribute__((address_space(3))) void*)(kb + e * 16),
                                         16, 0, 0);
      } else {
        int u = e - 256;
        int f = u >> 9;
        if (c == 13 && f == 1) continue;
        int j0 = c * 32 + f * 16;
        int r = (j0 >= 288) ? 2 : (j0 >= 144) ? 1 : 0;
        int kk = (r == 0) ? k : (r == 1) ? ((k + 63) & 63) : ((k + 1) & 63);
        int rowbase = kk * WIN + (j0 - r * 144);
        const char* gp = (const char*)yt + ((size_t)b * L + rowbase) * 512 + (size_t)(u & 511) * 16;
        __builtin_amdgcn_global_load_lds((const __attribute__((address_space(1))) void*)gp,
                                         (__attribute__((address_space(3))) void*)(vb + u * 16),
                                         16, 0, 0);
      }
    }
  };

  auto compute = [&](int c, int buf) {
    char* kb = lds + buf * 20480;
    char* vb = kb + 4096;
    int nm = (c == 13) ? 1 : 2;
    f32x4 sa[2];
    sa[0] = (f32x4){0.f, 0.f, 0.f, 0.f};
    sa[1] = (f32x4){0.f, 0.f, 0.f, 0.f};
#pragma unroll
    for (int m = 0; m < 2; ++m)
      if (m < nm) {
        int row32 = m * 16 + kr;
#pragma unroll
        for (int s = 0; s < 2; ++s) {
          int off = row32 * 128 + (((4 * s + g) ^ (row32 & 7)) * 16);
          s8v kf = *(const s8v*)(kb + off);
          sa[m] = __builtin_amdgcn_mfma_f32_16x16x32_bf16(kf, qf[s], sa[m], 0, 0, 0);
        }
      }
    float p[2][4];
    float mx = -3e38f;
#pragma unroll
    for (int m = 0; m < 2; ++m)
#pragma unroll
      for (int r = 0; r < 4; ++r) {
        float v = (m < nm) ? sa[m][r] * qn : -3e38f;
        p[m][r] = v;
        mx = fmaxf(mx, v);
      }
    mx = fmaxf(mx, __shfl_xor(mx, 16));
    mx = fmaxf(mx, __shfl_xor(mx, 32));
    float newm = fmaxf(runm, mx);
    float corr = __expf(runm - newm);
    runm = newm;
    float psum = 0.f;
#pragma unroll
    for (int m = 0; m < 2; ++m)
#pragma unroll
      for (int r = 0; r < 4; ++r) {
        float pv = __expf(p[m][r] - newm);
        p[m][r] = pv;
        psum += pv;
      }
    runsum = runsum * corr + psum;
    if (__any(corr < 1.0f)) {
      float f0 = __shfl(corr, 4 * g + 0);
      float f1 = __shfl(corr, 4 * g + 1);
      float f2 = __shfl(corr, 4 * g + 2);
      float f3 = __shfl(corr, 4 * g + 3);
#pragma unroll
      for (int nf = 0; nf < 16; ++nf) {
        acc[nf][0] *= f0; acc[nf][1] *= f1; acc[nf][2] *= f2; acc[nf][3] *= f3;
      }
    }
    s8v pa;
#pragma unroll
    for (int e2 = 0; e2 < 8; ++e2) pa[e2] = f2bf(p[e2 >> 2][e2 & 3]);
#pragma unroll
    for (int nf = 0; nf < 16; ++nf) {
      int cch = nf * 16 + kr;
      int grp = g ^ ((cch >> 2) & 3);
      s4v lo = *(const s4v*)(vb + cch * 32 + grp * 8);
      s4v hi = *(const s4v*)(vb + 8192 + cch * 32 + grp * 8);
      s8v bfv = __builtin_shufflevector(lo, hi, 0, 1, 2, 3, 4, 5, 6, 7);
      acc[nf] = __builtin_amdgcn_mfma_f32_16x16x32_bf16(pa, bfv, acc[nf], 0, 0, 0);
    }
  };

  stage(0, 0);
  __syncthreads();
  for (int c = 0; c < 14; ++c) {
    if (c < 13) stage(c + 1, (c + 1) & 1);
    compute(c, c & 1);
    __syncthreads();
  }

  runsum += __shfl_xor(runsum, 16);
  runsum += __shfl_xor(runsum, 32);
  float inv = 1.0f / runsum;
  float invr[4];
  int lorig[4];
#pragma unroll
  for (int r = 0; r < 4; ++r) {
    invr[r] = __shfl(inv, 4 * g + r);
    lorig[r] = sidx[b * L + qr0 + 4 * g + r];
  }
#pragma unroll
  for (int nf = 0; nf < 16; ++nf)
#pragma unroll
    for (int r = 0; r < 4; ++r)
      retb[((size_t)b * L + lorig[r]) * 256 + nf * 16 + kr] = acc[nf][r] * invr[r];
}

// ---------------- K7: transpose + residual ----------------
__global__ __launch_bounds__(256) void k_final(const float* __restrict__ in,
                                               const float* __restrict__ retb,
                                               float* __restrict__ out) {
  int lt = blockIdx.x, ct = blockIdx.y, b = blockIdx.z;
  int l0 = lt * 32, c0 = ct * 32;
  __shared__ float t_s[32][33];
  int t = threadIdx.x;
  for (int e = t; e < 1024; e += 256) {
    int i = e >> 5, j = e & 31;
    t_s[i][j] = retb[((size_t)b * L + l0 + i) * 256 + c0 + j];
  }
  __syncthreads();
  for (int e = t; e < 1024; e += 256) {
    int ci = e >> 5, lj = e & 31;
    size_t o = ((size_t)b * CC + c0 + ci) * L + l0 + lj;
    out[o] = in[o] + 0.1f * t_s[lj][ci];
  }
}

extern "C" void kernel_launch(void* const* d_in, const int* in_sizes, int n_in,
                              void* d_out, int out_size, void* d_ws, size_t ws_size,
                              hipStream_t stream) {
  const float* input = (const float*)d_in[0];
  const float* wm = (const float*)d_in[1];
  const float* bm = (const float*)d_in[2];
  const float* wa = (const float*)d_in[3];
  const float* ba = (const float*)d_in[4];
  const float* means = (const float*)d_in[5];
  float* out = (float*)d_out;

  float* ws = (float*)d_ws;
  float* x_embed = ws;                                      // 4,718,592 f
  float* y_embed = ws + 4718592ull;                         // 18,874,368 f (aliased: xhi/xlo, retb)
  float* retb = y_embed;
  unsigned short* xk = (unsigned short*)(ws + 23592960ull); // 4,718,592 bf16 (aliased: whiB/wloB)
  unsigned short* yt = (unsigned short*)(ws + 25952256ull); // 18,874,368 bf16
  float* norms = ws + 35389440ull;                          // 73,728 f
  int* buckets = (int*)(ws + 35463168ull);                  // 73,728 i
  int* sidx = buckets + 73728;                              // 73,728 i
  // conv3 temporaries (dead before their aliases are written):
  unsigned short* xhi = (unsigned short*)y_embed;           // 18,874,368 bf16
  unsigned short* xlo = xhi + 18874368ull;                  //  (fills y_embed region exactly)
  unsigned short* whiB = xk;                                // 294,912 bf16
  unsigned short* wloB = whiB + 294912ull;                  // 294,912 bf16

  k_isplit<<<dim3(96, 16, 8), 256, 0, stream>>>(input, xhi, xlo);
  k_wsplit<<<dim3(576), 256, 0, stream>>>(wm, whiB, wloB);
  k_conv3<<<dim3(96, 8), 384, 0, stream>>>(xhi, xlo, whiB, wloB, bm, x_embed);
  k_conv1<<<dim3(144, 4, 8), 256, 0, stream>>>(input, wa, ba, y_embed);
  k_bucket<<<dim3(288, 8), 256, 0, stream>>>(x_embed, means, buckets);
  k_sort<<<dim3(8), 256, 0, stream>>>(buckets, sidx);
  k_gather<<<dim3(144, 8), 256, 0, stream>>>(x_embed, y_embed, sidx, xk, yt, norms);
  k_attn<<<dim3(3, 64, 8), 192, 0, stream>>>(xk, yt, norms, sidx, retb);
  k_final<<<dim3(288, 8, 8), 256, 0, stream>>>(input, retb, out);
}

// Round 11
// 330.257 us; speedup vs baseline: 17.3972x; 1.3673x over previous
//
#include <hip/hip_runtime.h>
#include <math.h>

#define L 9216
#define HH 96
#define WW 96
#define CC 256
#define CR 64
#define NCLUST 128
#define WIN 144
#define NK 64   // L/WIN

typedef float f32x4 __attribute__((ext_vector_type(4)));
typedef float f32x16 __attribute__((ext_vector_type(16)));
typedef short s8v __attribute__((ext_vector_type(8)));
typedef short s4v __attribute__((ext_vector_type(4)));

static __device__ __forceinline__ short f2bf(float x) {
  union { float f; unsigned u; } v; v.f = x;
  unsigned r = (v.u + 0x7FFF + ((v.u >> 16) & 1)) >> 16;
  return (short)r;
}
static __device__ __forceinline__ float bf2f(short h) {
  union { float f; unsigned u; } v;
  v.u = ((unsigned)(unsigned short)h) << 16;
  return v.f;
}

// ---------------- K0a: input split fp32 -> xhi/xlo bf16, layout [b][h][icc16][w96][ic16] ----------------
__global__ __launch_bounds__(256) void k_isplit(const float* __restrict__ in,
                                                unsigned short* __restrict__ xhi,
                                                unsigned short* __restrict__ xlo) {
  int h = blockIdx.x, icc = blockIdx.y, b = blockIdx.z;
  __shared__ float tile[16][97];
  int t = threadIdx.x;
  for (int e = t; e < 1536; e += 256) {
    int ic = e / 96, w = e % 96;
    tile[ic][w] = in[((size_t)(b * 256 + icc * 16 + ic)) * L + h * 96 + w];
  }
  __syncthreads();
  size_t base = (((size_t)b * 96 + h) * 16 + icc) * 1536;
  for (int e = t; e < 1536; e += 256) {
    int w = e >> 4, ic = e & 15;
    float v = tile[ic][w];
    short hi = f2bf(v);
    float rv = v - bf2f(hi);
    short lo = f2bf(rv);
    xhi[base + e] = (unsigned short)hi;
    xlo[base + e] = (unsigned short)lo;
  }
}

// ---------------- K0b: conv3 weight split -> whiB/wloB [icc][tap][oc64][ic16] bf16 ----------------
__global__ __launch_bounds__(256) void k_wsplit(const float* __restrict__ wm,
                                                unsigned short* __restrict__ whiB,
                                                unsigned short* __restrict__ wloB) {
  int idx = blockIdx.x * 256 + threadIdx.x;
  if (idx < 147456) {
    int ic = idx & 15;
    int oc = (idx >> 4) & 63;
    int g = idx >> 10;
    int tap = g % 9, icc = g / 9;
    float v = wm[(size_t)oc * 2304 + (icc * 16 + ic) * 9 + tap];
    short hi = f2bf(v);
    float rv = v - bf2f(hi);
    whiB[idx] = (unsigned short)hi;
    wloB[idx] = (unsigned short)f2bf(rv);
  }
}

// ---------------- K0c: conv1 weight prep -> wt1 [icc][oc256][ic16] bf16 ----------------
__global__ __launch_bounds__(256) void k_w1prep(const float* __restrict__ wa,
                                                unsigned short* __restrict__ wt1) {
  int idx = blockIdx.x * 256 + threadIdx.x;  // 65536 total
  int ic = idx & 15, oc = (idx >> 4) & 255, icc = idx >> 12;
  wt1[idx] = (unsigned short)f2bf(wa[(size_t)oc * 256 + icc * 16 + ic]);
}

// ---------------- K1: conv3x3 via MFMA (split-bf16, 3 products) ----------------
// grid (96 rows, 8 b), 384 thr = 6 waves; wave = (pt 0..2 [32 pixels], ot 0..1 [32 oc]).
// LDS: input only, [buf][split][row3][col98][ic16] bf16; weights streamed from global (L2).
__global__ __launch_bounds__(384) void k_conv3(const unsigned short* __restrict__ xhi,
                                               const unsigned short* __restrict__ xlo,
                                               const unsigned short* __restrict__ whiB,
                                               const unsigned short* __restrict__ wloB,
                                               const float* __restrict__ bm,
                                               float* __restrict__ xe) {
  int h = blockIdx.x, b = blockIdx.y;
  __shared__ __align__(16) unsigned short lds[2 * 2 * 3 * 98 * 16];  // 37632 B
  int t = threadIdx.x;
  int wave = t >> 6, lane = t & 63;
  int pt = wave % 3, ot = wave / 3;
  int hh = lane >> 5, j = lane & 31;
  int r = lane & 31;

  // zero the halo column slots (0 and 97) of all 2x2x3 planes
  if (t < 384) {
    int slot = t >> 4, ic = t & 15;
    int bs = slot / 6, rem = slot % 6;
    int rr = rem >> 1, cc = rem & 1;
    lds[bs * 4704 + rr * 1568 + (cc ? 97 : 0) * 16 + ic] = 0;
  }

  f32x16 acc = {};

  auto stage = [&](int icc, int buf) {
#pragma unroll
    for (int k3 = 0; k3 < 3; ++k3) {
      int u = t + k3 * 384;
      int s = u / 576;
      int rem = u - s * 576;
      int rr = rem / 192;
      int q = rem - rr * 192;
      int gr = h - 1 + rr;
      unsigned short* dst = &lds[(buf * 2 + s) * 4704 + rr * 1568 + 16 + q * 8];
      if (gr >= 0 && gr < 96) {
        const unsigned short* src =
            (s ? xlo : xhi) + ((((size_t)b * 96 + gr) * 16 + icc) * 1536 + q * 8);
        __builtin_amdgcn_global_load_lds((const __attribute__((address_space(1))) void*)src,
                                         (__attribute__((address_space(3))) void*)dst, 16, 0, 0);
      } else {
        *(s8v*)dst = (s8v){0, 0, 0, 0, 0, 0, 0, 0};
      }
    }
  };

  auto compute = [&](int icc, int buf) {
    const unsigned short* lbase = lds + buf * 9408;
    const unsigned short* wb = whiB + (size_t)icc * 9216;  // 9 taps * 1024
    const unsigned short* wl = wloB + (size_t)icc * 9216;
#pragma unroll
    for (int kh = 0; kh < 3; ++kh)
#pragma unroll
      for (int kw = 0; kw < 3; ++kw) {
        int tap = kh * 3 + kw;
        int aidx = kh * 1568 + (pt * 32 + r + kw) * 16 + hh * 8;
        s8v a_hi = *(const s8v*)(lbase + aidx);
        s8v a_lo = *(const s8v*)(lbase + 4704 + aidx);
        int woff = tap * 1024 + (ot * 32 + j) * 16 + hh * 8;
        s8v b_hi = *(const s8v*)(wb + woff);
        s8v b_lo = *(const s8v*)(wl + woff);
        acc = __builtin_amdgcn_mfma_f32_32x32x16_bf16(a_hi, b_hi, acc, 0, 0, 0);
        acc = __builtin_amdgcn_mfma_f32_32x32x16_bf16(a_hi, b_lo, acc, 0, 0, 0);
        acc = __builtin_amdgcn_mfma_f32_32x32x16_bf16(a_lo, b_hi, acc, 0, 0, 0);
      }
  };

  stage(0, 0);
  __syncthreads();
#pragma unroll 1
  for (int icc = 0; icc < 16; ++icc) {
    int buf = icc & 1;
    if (icc < 15) stage(icc + 1, buf ^ 1);
    compute(icc, buf);
    __syncthreads();
  }

  float bv = bm[ot * 32 + j];
#pragma unroll
  for (int reg = 0; reg < 16; ++reg) {
    int prow = (reg & 3) + 8 * (reg >> 2) + 4 * hh;
    xe[((size_t)b * L + h * 96 + pt * 32 + prow) * 64 + ot * 32 + j] = acc[reg] + bv;
  }
}

// ---------------- K2: conv1x1 via MFMA bf16 (no LDS, no barriers) ----------------
// grid (96 rows, 8 b), 384 thr = 6 waves; wave = (pt 0..2 [32 px], ot 0..1 [128 oc]).
// A = xhi direct from global (k-contiguous ic16); B = wt1 streamed from L2. Output bf16.
__global__ __launch_bounds__(384) void k_conv1(const unsigned short* __restrict__ xhi,
                                               const unsigned short* __restrict__ wt1,
                                               const float* __restrict__ ba,
                                               unsigned short* __restrict__ yeb) {
  int h = blockIdx.x, b = blockIdx.y;
  int t = threadIdx.x;
  int wave = t >> 6, lane = t & 63;
  int pt = wave % 3, ot = wave / 3;
  int hh = lane >> 5, j = lane & 31;
  int r = lane & 31;

  f32x16 acc[4] = {};
  const unsigned short* abase =
      xhi + (((size_t)b * 96 + h) * 16) * 1536 + (pt * 32 + r) * 16 + hh * 8;
  const unsigned short* bbase = wt1 + (ot * 128 + j) * 16 + hh * 8;
#pragma unroll 2
  for (int icc = 0; icc < 16; ++icc) {
    s8v av = *(const s8v*)(abase + icc * 1536);
    const unsigned short* bp = bbase + icc * 4096;
#pragma unroll
    for (int tile = 0; tile < 4; ++tile) {
      s8v bv = *(const s8v*)(bp + tile * 512);
      acc[tile] = __builtin_amdgcn_mfma_f32_32x32x16_bf16(av, bv, acc[tile], 0, 0, 0);
    }
  }
#pragma unroll
  for (int tile = 0; tile < 4; ++tile) {
    int oc = ot * 128 + tile * 32 + j;
    float bias = ba[oc];
#pragma unroll
    for (int reg = 0; reg < 16; ++reg) {
      int prow = (reg & 3) + 8 * (reg >> 2) + 4 * hh;
      yeb[((size_t)b * L + h * 96 + pt * 32 + prow) * 256 + oc] =
          (unsigned short)f2bf(acc[tile][reg] + bias);
    }
  }
}

// ---------------- K3: buckets = argmax_c(x . mean_c) ----------------
__global__ __launch_bounds__(256) void k_bucket(const float* __restrict__ xe,
                                                const float* __restrict__ means,
                                                int* __restrict__ buckets) {
  int lt = blockIdx.x, b = blockIdx.y;
  int l0 = lt * 32;
  __shared__ float x_s[32 * 65];
  __shared__ float m_s[128 * 65];
  __shared__ float bv_s[32 * 8];
  __shared__ int bi_s[32 * 8];
  int t = threadIdx.x;
  for (int e = t; e < 2048; e += 256) {
    int px = e >> 6, d = e & 63;
    x_s[px * 65 + d] = xe[((size_t)b * L + l0) * 64 + e];
  }
  for (int e = t; e < 8192; e += 256) {
    int c = e >> 6, d = e & 63;
    m_s[c * 65 + d] = means[e];
  }
  __syncthreads();
  int px = t >> 3, cg = t & 7;
  float best = -1e30f;
  int bidx = 0;
  const float* xr = &x_s[px * 65];
  for (int cc = 0; cc < 16; ++cc) {
    int c = cg + 8 * cc;
    const float* mr = &m_s[c * 65];
    float d = 0.f;
#pragma unroll
    for (int dd = 0; dd < 64; ++dd) d += xr[dd] * mr[dd];
    if (d > best || (d == best && c < bidx)) { best = d; bidx = c; }
  }
  bv_s[px * 8 + cg] = best;
  bi_s[px * 8 + cg] = bidx;
  __syncthreads();
  if (cg == 0) {
    float bb = bv_s[px * 8];
    int bbi = bi_s[px * 8];
    for (int g = 1; g < 8; ++g) {
      float v = bv_s[px * 8 + g];
      int vi = bi_s[px * 8 + g];
      if (v > bb || (v == bb && vi < bbi)) { bb = v; bbi = vi; }
    }
    buckets[b * L + l0 + px] = bbi;
  }
}

// ---------------- K4: parallel stable counting sort ----------------
#define SCH 256
#define CHL 36
__global__ __launch_bounds__(256) void k_sort(const int* __restrict__ buckets,
                                              int* __restrict__ sidx) {
  int b = blockIdx.x, t = threadIdx.x;
  __shared__ int keys_s[L];
  __shared__ unsigned short cnt_s[SCH][130];
  __shared__ int halfsum0[NCLUST];
  __shared__ int keytotal[NCLUST];
  __shared__ int keybase[NCLUST];
  const int* bk = buckets + b * L;
  for (int i = t; i < L; i += SCH) keys_s[i] = bk[i];
  for (int i = 0; i < 130; ++i) cnt_s[t][i] = 0;
  __syncthreads();
  {
    int base = t * CHL;
    for (int i = 0; i < CHL; ++i) cnt_s[t][keys_s[base + i]]++;
  }
  __syncthreads();
  {
    int kkey = t & 127, h = t >> 7;
    int c0 = h * 128;
    int run = 0;
    for (int c = 0; c < 128; ++c) {
      int v = cnt_s[c0 + c][kkey];
      cnt_s[c0 + c][kkey] = (unsigned short)run;
      run += v;
    }
    if (h == 0) halfsum0[kkey] = run;
    else keytotal[kkey] = run;
  }
  __syncthreads();
  if (t < NCLUST) keytotal[t] += halfsum0[t];
  __syncthreads();
  if (t == 0) {
    int s = 0;
    for (int i = 0; i < NCLUST; ++i) { keybase[i] = s; s += keytotal[i]; }
  }
  __syncthreads();
  {
    int h = t >> 7;
    int base = t * CHL;
    int* sb = sidx + b * L;
    for (int i = 0; i < CHL; ++i) {
      int kkey = keys_s[base + i];
      int pos = keybase[kkey] + (h ? halfsum0[kkey] : 0) + cnt_s[t][kkey];
      cnt_s[t][kkey]++;
      sb[pos] = base + i;
    }
  }
}

// ---------------- K5: gather + normalize -> xk (bf16 swizzled), yt (bf16 V^T tiles) ----------------
__global__ __launch_bounds__(256) void k_gather(const float* __restrict__ xe,
                                                const unsigned short* __restrict__ yeb,
                                                const int* __restrict__ sidx,
                                                unsigned short* __restrict__ xk,
                                                unsigned short* __restrict__ yt,
                                                float* __restrict__ norms) {
  int it = blockIdx.x, b = blockIdx.y;
  int i0 = it * 64;
  __shared__ float x_s[64 * 65];
  __shared__ unsigned short y_s[16 * 260];
  __shared__ int idx_s[64];
  __shared__ float scale_s[64];
  int t = threadIdx.x;
  if (t < 64) idx_s[t] = sidx[b * L + i0 + t];
  __syncthreads();
  for (int e = t; e < 4096; e += 256) {
    int i = e >> 6, d = e & 63;
    x_s[i * 65 + d] = xe[((size_t)b * L + idx_s[i]) * 64 + d];
  }
  __syncthreads();
  if (t < 64) {
    float s = 0.f;
    const float* xr = &x_s[t * 65];
#pragma unroll
    for (int d = 0; d < 64; ++d) s += xr[d] * xr[d];
    float n = fmaxf(sqrtf(s), 5e-5f);
    norms[b * L + i0 + t] = n;
    scale_s[t] = 1.0f / n;
  }
  __syncthreads();
  for (int e = t; e < 4096; e += 256) {
    int i = e >> 6, d = e & 63;
    int ig = i0 + i;
    int db = (((d >> 3) ^ (ig & 7)) << 3) | (d & 7);
    xk[((size_t)b * L + ig) * 64 + db] = (unsigned short)f2bf(x_s[i * 65 + d] * scale_s[i]);
  }
  for (int tile = 0; tile < 4; ++tile) {
    for (int e = t; e < 4096; e += 256) {
      int i16 = e >> 8, c = e & 255;
      y_s[i16 * 260 + c] = yeb[((size_t)b * L + idx_s[tile * 16 + i16]) * 256 + c];
    }
    __syncthreads();
    size_t tb = (size_t)b * L * 256 + (size_t)((i0 >> 4) + tile) * 4096;
    for (int e = t; e < 4096; e += 256) {
      int c = e >> 4, k16 = e & 15;
      int sw = ((((k16 >> 2) ^ ((c >> 2) & 3)) << 2) | (k16 & 3));
      yt[tb + c * 16 + sw] = y_s[k16 * 260 + c];
    }
    __syncthreads();
  }
}

// ---------------- K6: flash MFMA attention ----------------
__global__ __launch_bounds__(192, 3) void k_attn(const unsigned short* __restrict__ xk,
                                                 const unsigned short* __restrict__ yt,
                                                 const float* __restrict__ norms,
                                                 const int* __restrict__ sidx,
                                                 float* __restrict__ retb) {
  int qc = blockIdx.x, k = blockIdx.y, b = blockIdx.z;
  __shared__ __align__(16) char lds[40960];
  int t = threadIdx.x;
  int lane = t & 63;
  int g = lane >> 4, kr = lane & 15;
  int kbase = k * WIN;
  int qr0 = kbase + qc * 48 + (t >> 6) * 16;
  int qrow = qr0 + kr;

  s8v qf[2];
#pragma unroll
  for (int s = 0; s < 2; ++s) {
    int blk = (4 * s + g) ^ (qrow & 7);
    qf[s] = *(const s8v*)(xk + ((size_t)b * L + qrow) * 64 + blk * 8);
  }
  float qn = norms[(size_t)b * L + qrow];

  f32x4 acc[16];
#pragma unroll
  for (int nf = 0; nf < 16; ++nf) acc[nf] = (f32x4){0.f, 0.f, 0.f, 0.f};
  float runm = -3e38f, runsum = 0.f;

  auto stage = [&](int c, int buf) {
    char* kb = lds + buf * 20480;
    char* vb = kb + 4096;
    for (int e = t; e < 1280; e += 192) {
      if (e < 256) {
        int key32 = e >> 3;
        if (c == 13 && key32 >= 16) continue;
        int j = c * 32 + key32;
        int r = (j >= 288) ? 2 : (j >= 144) ? 1 : 0;
        int kk = (r == 0) ? k : (r == 1) ? ((k + 63) & 63) : ((k + 1) & 63);
        int phys = kk * WIN + (j - r * 144);
        const char* gp = (const char*)xk + (((size_t)b * L + phys) * 64 + (e & 7) * 8) * 2;
        __builtin_amdgcn_global_load_lds((const __attribute__((address_space(1))) void*)gp,
                                         (__attribute__((address_space(3))) void*)(kb + e * 16),
                                         16, 0, 0);
      } else {
        int u = e - 256;
        int f = u >> 9;
        if (c == 13 && f == 1) continue;
        int j0 = c * 32 + f * 16;
        int r = (j0 >= 288) ? 2 : (j0 >= 144) ? 1 : 0;
        int kk = (r == 0) ? k : (r == 1) ? ((k + 63) & 63) : ((k + 1) & 63);
        int rowbase = kk * WIN + (j0 - r * 144);
        const char* gp = (const char*)yt + ((size_t)b * L + rowbase) * 512 + (size_t)(u & 511) * 16;
        __builtin_amdgcn_global_load_lds((const __attribute__((address_space(1))) void*)gp,
                                         (__attribute__((address_space(3))) void*)(vb + u * 16),
                                         16, 0, 0);
      }
    }
  };

  auto compute = [&](int c, int buf) {
    char* kb = lds + buf * 20480;
    char* vb = kb + 4096;
    int nm = (c == 13) ? 1 : 2;
    f32x4 sa[2];
    sa[0] = (f32x4){0.f, 0.f, 0.f, 0.f};
    sa[1] = (f32x4){0.f, 0.f, 0.f, 0.f};
#pragma unroll
    for (int m = 0; m < 2; ++m)
      if (m < nm) {
        int row32 = m * 16 + kr;
#pragma unroll
        for (int s = 0; s < 2; ++s) {
          int off = row32 * 128 + (((4 * s + g) ^ (row32 & 7)) * 16);
          s8v kf = *(const s8v*)(kb + off);
          sa[m] = __builtin_amdgcn_mfma_f32_16x16x32_bf16(kf, qf[s], sa[m], 0, 0, 0);
        }
      }
    float p[2][4];
    float mx = -3e38f;
#pragma unroll
    for (int m = 0; m < 2; ++m)
#pragma unroll
      for (int r = 0; r < 4; ++r) {
        float v = (m < nm) ? sa[m][r] * qn : -3e38f;
        p[m][r] = v;
        mx = fmaxf(mx, v);
      }
    mx = fmaxf(mx, __shfl_xor(mx, 16));
    mx = fmaxf(mx, __shfl_xor(mx, 32));
    float newm = fmaxf(runm, mx);
    float corr = __expf(runm - newm);
    runm = newm;
    float psum = 0.f;
#pragma unroll
    for (int m = 0; m < 2; ++m)
#pragma unroll
      for (int r = 0; r < 4; ++r) {
        float pv = __expf(p[m][r] - newm);
        p[m][r] = pv;
        psum += pv;
      }
    runsum = runsum * corr + psum;
    if (__any(corr < 1.0f)) {
      float f0 = __shfl(corr, 4 * g + 0);
      float f1 = __shfl(corr, 4 * g + 1);
      float f2 = __shfl(corr, 4 * g + 2);
      float f3 = __shfl(corr, 4 * g + 3);
#pragma unroll
      for (int nf = 0; nf < 16; ++nf) {
        acc[nf][0] *= f0; acc[nf][1] *= f1; acc[nf][2] *= f2; acc[nf][3] *= f3;
      }
    }
    s8v pa;
#pragma unroll
    for (int e2 = 0; e2 < 8; ++e2) pa[e2] = f2bf(p[e2 >> 2][e2 & 3]);
#pragma unroll
    for (int nf = 0; nf < 16; ++nf) {
      int cch = nf * 16 + kr;
      int grp = g ^ ((cch >> 2) & 3);
      s4v lo = *(const s4v*)(vb + cch * 32 + grp * 8);
      s4v hi = *(const s4v*)(vb + 8192 + cch * 32 + grp * 8);
      s8v bfv = __builtin_shufflevector(lo, hi, 0, 1, 2, 3, 4, 5, 6, 7);
      acc[nf] = __builtin_amdgcn_mfma_f32_16x16x32_bf16(pa, bfv, acc[nf], 0, 0, 0);
    }
  };

  stage(0, 0);
  __syncthreads();
  for (int c = 0; c < 14; ++c) {
    if (c < 13) stage(c + 1, (c + 1) & 1);
    compute(c, c & 1);
    __syncthreads();
  }

  runsum += __shfl_xor(runsum, 16);
  runsum += __shfl_xor(runsum, 32);
  float inv = 1.0f / runsum;
  float invr[4];
  int lorig[4];
#pragma unroll
  for (int r = 0; r < 4; ++r) {
    invr[r] = __shfl(inv, 4 * g + r);
    lorig[r] = sidx[b * L + qr0 + 4 * g + r];
  }
#pragma unroll
  for (int nf = 0; nf < 16; ++nf)
#pragma unroll
    for (int r = 0; r < 4; ++r)
      retb[((size_t)b * L + lorig[r]) * 256 + nf * 16 + kr] = acc[nf][r] * invr[r];
}

// ---------------- K7: transpose + residual ----------------
__global__ __launch_bounds__(256) void k_final(const float* __restrict__ in,
                                               const float* __restrict__ retb,
                                               float* __restrict__ out) {
  int lt = blockIdx.x, ct = blockIdx.y, b = blockIdx.z;
  int l0 = lt * 32, c0 = ct * 32;
  __shared__ float t_s[32][33];
  int t = threadIdx.x;
  for (int e = t; e < 1024; e += 256) {
    int i = e >> 5, j = e & 31;
    t_s[i][j] = retb[((size_t)b * L + l0 + i) * 256 + c0 + j];
  }
  __syncthreads();
  for (int e = t; e < 1024; e += 256) {
    int ci = e >> 5, lj = e & 31;
    size_t o = ((size_t)b * CC + c0 + ci) * L + l0 + lj;
    out[o] = in[o] + 0.1f * t_s[lj][ci];
  }
}

extern "C" void kernel_launch(void* const* d_in, const int* in_sizes, int n_in,
                              void* d_out, int out_size, void* d_ws, size_t ws_size,
                              hipStream_t stream) {
  const float* input = (const float*)d_in[0];
  const float* wm = (const float*)d_in[1];
  const float* bm = (const float*)d_in[2];
  const float* wa = (const float*)d_in[3];
  const float* ba = (const float*)d_in[4];
  const float* means = (const float*)d_in[5];
  float* out = (float*)d_out;

  float* ws = (float*)d_ws;
  float* x_embed = ws;                                      // 4,718,592 f
  float* y_embed = ws + 4718592ull;                         // 18,874,368 f (aliased: xhi/yeb, retb)
  float* retb = y_embed;
  unsigned short* xk = (unsigned short*)(ws + 23592960ull); // 4,718,592 bf16 (aliased: w bufs)
  unsigned short* yt = (unsigned short*)(ws + 25952256ull); // 18,874,368 bf16
  float* norms = ws + 35389440ull;                          // 73,728 f
  int* buckets = (int*)(ws + 35463168ull);                  // 73,728 i
  int* sidx = buckets + 73728;                              // 73,728 i
  // conv temporaries (dead before their aliases are written):
  unsigned short* xhi = (unsigned short*)y_embed;           // 18,874,368 bf16 (first half)
  unsigned short* xlo = xhi + 18874368ull;                  // second half; becomes yeb
  unsigned short* yeb = xlo;                                // conv1 bf16 output (xlo dead after conv3)
  unsigned short* whiB = xk;                                // 294,912 bf16
  unsigned short* wloB = whiB + 294912ull;                  // 294,912 bf16
  unsigned short* wt1 = wloB + 294912ull;                   // 65,536 bf16

  k_isplit<<<dim3(96, 16, 8), 256, 0, stream>>>(input, xhi, xlo);
  k_wsplit<<<dim3(576), 256, 0, stream>>>(wm, whiB, wloB);
  k_w1prep<<<dim3(256), 256, 0, stream>>>(wa, wt1);
  k_conv3<<<dim3(96, 8), 384, 0, stream>>>(xhi, xlo, whiB, wloB, bm, x_embed);
  k_conv1<<<dim3(96, 8), 384, 0, stream>>>(xhi, wt1, ba, yeb);
  k_bucket<<<dim3(288, 8), 256, 0, stream>>>(x_embed, means, buckets);
  k_sort<<<dim3(8), 256, 0, stream>>>(buckets, sidx);
  k_gather<<<dim3(144, 8), 256, 0, stream>>>(x_embed, yeb, sidx, xk, yt, norms);
  k_attn<<<dim3(3, 64, 8), 192, 0, stream>>>(xk, yt, norms, sidx, retb);
  k_final<<<dim3(288, 8, 8), 256, 0, stream>>>(input, retb, out);
}

// Round 12
// 306.705 us; speedup vs baseline: 18.7331x; 1.0768x over previous
//
#include <hip/hip_runtime.h>
#include <math.h>

#define L 9216
#define HH 96
#define WW 96
#define CC 256
#define CR 64
#define NCLUST 128
#define WIN 144
#define NK 64   // L/WIN

typedef float f32x4 __attribute__((ext_vector_type(4)));
typedef float f32x16 __attribute__((ext_vector_type(16)));
typedef short s8v __attribute__((ext_vector_type(8)));
typedef short s4v __attribute__((ext_vector_type(4)));

static __device__ __forceinline__ short f2bf(float x) {
  union { float f; unsigned u; } v; v.f = x;
  unsigned r = (v.u + 0x7FFF + ((v.u >> 16) & 1)) >> 16;
  return (short)r;
}
static __device__ __forceinline__ float bf2f(short h) {
  union { float f; unsigned u; } v;
  v.u = ((unsigned)(unsigned short)h) << 16;
  return v.f;
}

// ---------------- K0a: input split fp32 -> xhi/xlo bf16, layout [b][h][icc16][w96][ic16] ----------------
__global__ __launch_bounds__(256) void k_isplit(const float* __restrict__ in,
                                                unsigned short* __restrict__ xhi,
                                                unsigned short* __restrict__ xlo) {
  int h = blockIdx.x, icc = blockIdx.y, b = blockIdx.z;
  __shared__ float tile[16][97];
  int t = threadIdx.x;
  for (int e = t; e < 1536; e += 256) {
    int ic = e / 96, w = e % 96;
    tile[ic][w] = in[((size_t)(b * 256 + icc * 16 + ic)) * L + h * 96 + w];
  }
  __syncthreads();
  size_t base = (((size_t)b * 96 + h) * 16 + icc) * 1536;
  for (int e = t; e < 1536; e += 256) {
    int w = e >> 4, ic = e & 15;
    float v = tile[ic][w];
    short hi = f2bf(v);
    float rv = v - bf2f(hi);
    short lo = f2bf(rv);
    xhi[base + e] = (unsigned short)hi;
    xlo[base + e] = (unsigned short)lo;
  }
}

// ---------------- K0b: conv3 weight split -> whiB/wloB [icc][tap][oc64][ic16] bf16 ----------------
__global__ __launch_bounds__(256) void k_wsplit(const float* __restrict__ wm,
                                                unsigned short* __restrict__ whiB,
                                                unsigned short* __restrict__ wloB) {
  int idx = blockIdx.x * 256 + threadIdx.x;
  if (idx < 147456) {
    int ic = idx & 15;
    int oc = (idx >> 4) & 63;
    int g = idx >> 10;
    int tap = g % 9, icc = g / 9;
    float v = wm[(size_t)oc * 2304 + (icc * 16 + ic) * 9 + tap];
    short hi = f2bf(v);
    float rv = v - bf2f(hi);
    whiB[idx] = (unsigned short)hi;
    wloB[idx] = (unsigned short)f2bf(rv);
  }
}

// ---------------- K0c: conv1 weight prep -> wt1 [icc][oc256][ic16] bf16 ----------------
__global__ __launch_bounds__(256) void k_w1prep(const float* __restrict__ wa,
                                                unsigned short* __restrict__ wt1) {
  int idx = blockIdx.x * 256 + threadIdx.x;  // 65536 total
  int ic = idx & 15, oc = (idx >> 4) & 255, icc = idx >> 12;
  wt1[idx] = (unsigned short)f2bf(wa[(size_t)oc * 256 + icc * 16 + ic]);
}

// ---------------- K1: conv3x3 via MFMA (split-bf16, 3 products) ----------------
__global__ __launch_bounds__(384) void k_conv3(const unsigned short* __restrict__ xhi,
                                               const unsigned short* __restrict__ xlo,
                                               const unsigned short* __restrict__ whiB,
                                               const unsigned short* __restrict__ wloB,
                                               const float* __restrict__ bm,
                                               float* __restrict__ xe) {
  int h = blockIdx.x, b = blockIdx.y;
  __shared__ __align__(16) unsigned short lds[2 * 2 * 3 * 98 * 16];  // 37632 B
  int t = threadIdx.x;
  int wave = t >> 6, lane = t & 63;
  int pt = wave % 3, ot = wave / 3;
  int hh = lane >> 5, j = lane & 31;
  int r = lane & 31;

  if (t < 384) {
    int slot = t >> 4, ic = t & 15;
    int bs = slot / 6, rem = slot % 6;
    int rr = rem >> 1, cc = rem & 1;
    lds[bs * 4704 + rr * 1568 + (cc ? 97 : 0) * 16 + ic] = 0;
  }

  f32x16 acc = {};

  auto stage = [&](int icc, int buf) {
#pragma unroll
    for (int k3 = 0; k3 < 3; ++k3) {
      int u = t + k3 * 384;
      int s = u / 576;
      int rem = u - s * 576;
      int rr = rem / 192;
      int q = rem - rr * 192;
      int gr = h - 1 + rr;
      unsigned short* dst = &lds[(buf * 2 + s) * 4704 + rr * 1568 + 16 + q * 8];
      if (gr >= 0 && gr < 96) {
        const unsigned short* src =
            (s ? xlo : xhi) + ((((size_t)b * 96 + gr) * 16 + icc) * 1536 + q * 8);
        __builtin_amdgcn_global_load_lds((const __attribute__((address_space(1))) void*)src,
                                         (__attribute__((address_space(3))) void*)dst, 16, 0, 0);
      } else {
        *(s8v*)dst = (s8v){0, 0, 0, 0, 0, 0, 0, 0};
      }
    }
  };

  auto compute = [&](int icc, int buf) {
    const unsigned short* lbase = lds + buf * 9408;
    const unsigned short* wb = whiB + (size_t)icc * 9216;
    const unsigned short* wl = wloB + (size_t)icc * 9216;
#pragma unroll
    for (int kh = 0; kh < 3; ++kh)
#pragma unroll
      for (int kw = 0; kw < 3; ++kw) {
        int tap = kh * 3 + kw;
        int aidx = kh * 1568 + (pt * 32 + r + kw) * 16 + hh * 8;
        s8v a_hi = *(const s8v*)(lbase + aidx);
        s8v a_lo = *(const s8v*)(lbase + 4704 + aidx);
        int woff = tap * 1024 + (ot * 32 + j) * 16 + hh * 8;
        s8v b_hi = *(const s8v*)(wb + woff);
        s8v b_lo = *(const s8v*)(wl + woff);
        acc = __builtin_amdgcn_mfma_f32_32x32x16_bf16(a_hi, b_hi, acc, 0, 0, 0);
        acc = __builtin_amdgcn_mfma_f32_32x32x16_bf16(a_hi, b_lo, acc, 0, 0, 0);
        acc = __builtin_amdgcn_mfma_f32_32x32x16_bf16(a_lo, b_hi, acc, 0, 0, 0);
      }
  };

  stage(0, 0);
  __syncthreads();
#pragma unroll 1
  for (int icc = 0; icc < 16; ++icc) {
    int buf = icc & 1;
    if (icc < 15) stage(icc + 1, buf ^ 1);
    compute(icc, buf);
    __syncthreads();
  }

  float bv = bm[ot * 32 + j];
#pragma unroll
  for (int reg = 0; reg < 16; ++reg) {
    int prow = (reg & 3) + 8 * (reg >> 2) + 4 * hh;
    xe[((size_t)b * L + h * 96 + pt * 32 + prow) * 64 + ot * 32 + j] = acc[reg] + bv;
  }
}

// ---------------- K2: conv1x1 via MFMA bf16 (no LDS, no barriers) ----------------
__global__ __launch_bounds__(384) void k_conv1(const unsigned short* __restrict__ xhi,
                                               const unsigned short* __restrict__ wt1,
                                               const float* __restrict__ ba,
                                               unsigned short* __restrict__ yeb) {
  int h = blockIdx.x, b = blockIdx.y;
  int t = threadIdx.x;
  int wave = t >> 6, lane = t & 63;
  int pt = wave % 3, ot = wave / 3;
  int hh = lane >> 5, j = lane & 31;
  int r = lane & 31;

  f32x16 acc[4] = {};
  const unsigned short* abase =
      xhi + (((size_t)b * 96 + h) * 16) * 1536 + (pt * 32 + r) * 16 + hh * 8;
  const unsigned short* bbase = wt1 + (ot * 128 + j) * 16 + hh * 8;
#pragma unroll 2
  for (int icc = 0; icc < 16; ++icc) {
    s8v av = *(const s8v*)(abase + icc * 1536);
    const unsigned short* bp = bbase + icc * 4096;
#pragma unroll
    for (int tile = 0; tile < 4; ++tile) {
      s8v bv = *(const s8v*)(bp + tile * 512);
      acc[tile] = __builtin_amdgcn_mfma_f32_32x32x16_bf16(av, bv, acc[tile], 0, 0, 0);
    }
  }
#pragma unroll
  for (int tile = 0; tile < 4; ++tile) {
    int oc = ot * 128 + tile * 32 + j;
    float bias = ba[oc];
#pragma unroll
    for (int reg = 0; reg < 16; ++reg) {
      int prow = (reg & 3) + 8 * (reg >> 2) + 4 * hh;
      yeb[((size_t)b * L + h * 96 + pt * 32 + prow) * 256 + oc] =
          (unsigned short)f2bf(acc[tile][reg] + bias);
    }
  }
}

// ---------------- K3: buckets = argmax_c(x . mean_c) ----------------
__global__ __launch_bounds__(256) void k_bucket(const float* __restrict__ xe,
                                                const float* __restrict__ means,
                                                int* __restrict__ buckets) {
  int lt = blockIdx.x, b = blockIdx.y;
  int l0 = lt * 32;
  __shared__ float x_s[32 * 65];
  __shared__ float m_s[128 * 65];
  __shared__ float bv_s[32 * 8];
  __shared__ int bi_s[32 * 8];
  int t = threadIdx.x;
  for (int e = t; e < 2048; e += 256) {
    int px = e >> 6, d = e & 63;
    x_s[px * 65 + d] = xe[((size_t)b * L + l0) * 64 + e];
  }
  for (int e = t; e < 8192; e += 256) {
    int c = e >> 6, d = e & 63;
    m_s[c * 65 + d] = means[e];
  }
  __syncthreads();
  int px = t >> 3, cg = t & 7;
  float best = -1e30f;
  int bidx = 0;
  const float* xr = &x_s[px * 65];
  for (int cc = 0; cc < 16; ++cc) {
    int c = cg + 8 * cc;
    const float* mr = &m_s[c * 65];
    float d = 0.f;
#pragma unroll
    for (int dd = 0; dd < 64; ++dd) d += xr[dd] * mr[dd];
    if (d > best || (d == best && c < bidx)) { best = d; bidx = c; }
  }
  bv_s[px * 8 + cg] = best;
  bi_s[px * 8 + cg] = bidx;
  __syncthreads();
  if (cg == 0) {
    float bb = bv_s[px * 8];
    int bbi = bi_s[px * 8];
    for (int g = 1; g < 8; ++g) {
      float v = bv_s[px * 8 + g];
      int vi = bi_s[px * 8 + g];
      if (v > bb || (v == bb && vi < bbi)) { bb = v; bbi = vi; }
    }
    buckets[b * L + l0 + px] = bbi;
  }
}

// ---------------- K4: parallel stable counting sort ----------------
#define SCH 256
#define CHL 36
__global__ __launch_bounds__(256) void k_sort(const int* __restrict__ buckets,
                                              int* __restrict__ sidx) {
  int b = blockIdx.x, t = threadIdx.x;
  __shared__ int keys_s[L];
  __shared__ unsigned short cnt_s[SCH][130];
  __shared__ int halfsum0[NCLUST];
  __shared__ int keytotal[NCLUST];
  __shared__ int keybase[NCLUST];
  const int* bk = buckets + b * L;
  for (int i = t; i < L; i += SCH) keys_s[i] = bk[i];
  for (int i = 0; i < 130; ++i) cnt_s[t][i] = 0;
  __syncthreads();
  {
    int base = t * CHL;
    for (int i = 0; i < CHL; ++i) cnt_s[t][keys_s[base + i]]++;
  }
  __syncthreads();
  {
    int kkey = t & 127, h = t >> 7;
    int c0 = h * 128;
    int run = 0;
    for (int c = 0; c < 128; ++c) {
      int v = cnt_s[c0 + c][kkey];
      cnt_s[c0 + c][kkey] = (unsigned short)run;
      run += v;
    }
    if (h == 0) halfsum0[kkey] = run;
    else keytotal[kkey] = run;
  }
  __syncthreads();
  if (t < NCLUST) keytotal[t] += halfsum0[t];
  __syncthreads();
  if (t == 0) {
    int s = 0;
    for (int i = 0; i < NCLUST; ++i) { keybase[i] = s; s += keytotal[i]; }
  }
  __syncthreads();
  {
    int h = t >> 7;
    int base = t * CHL;
    int* sb = sidx + b * L;
    for (int i = 0; i < CHL; ++i) {
      int kkey = keys_s[base + i];
      int pos = keybase[kkey] + (h ? halfsum0[kkey] : 0) + cnt_s[t][kkey];
      cnt_s[t][kkey]++;
      sb[pos] = base + i;
    }
  }
}

// ---------------- K5: gather + normalize -> xk (bf16 swizzled), yt (bf16 V^T tiles) ----------------
__global__ __launch_bounds__(256) void k_gather(const float* __restrict__ xe,
                                                const unsigned short* __restrict__ yeb,
                                                const int* __restrict__ sidx,
                                                unsigned short* __restrict__ xk,
                                                unsigned short* __restrict__ yt,
                                                float* __restrict__ norms) {
  int it = blockIdx.x, b = blockIdx.y;
  int i0 = it * 64;
  __shared__ float x_s[64 * 65];
  __shared__ unsigned short y_s[16 * 260];
  __shared__ int idx_s[64];
  __shared__ float scale_s[64];
  int t = threadIdx.x;
  if (t < 64) idx_s[t] = sidx[b * L + i0 + t];
  __syncthreads();
  for (int e = t; e < 4096; e += 256) {
    int i = e >> 6, d = e & 63;
    x_s[i * 65 + d] = xe[((size_t)b * L + idx_s[i]) * 64 + d];
  }
  __syncthreads();
  if (t < 64) {
    float s = 0.f;
    const float* xr = &x_s[t * 65];
#pragma unroll
    for (int d = 0; d < 64; ++d) s += xr[d] * xr[d];
    float n = fmaxf(sqrtf(s), 5e-5f);
    norms[b * L + i0 + t] = n;
    scale_s[t] = 1.0f / n;
  }
  __syncthreads();
  for (int e = t; e < 4096; e += 256) {
    int i = e >> 6, d = e & 63;
    int ig = i0 + i;
    int db = (((d >> 3) ^ (ig & 7)) << 3) | (d & 7);
    xk[((size_t)b * L + ig) * 64 + db] = (unsigned short)f2bf(x_s[i * 65 + d] * scale_s[i]);
  }
  for (int tile = 0; tile < 4; ++tile) {
    for (int e = t; e < 4096; e += 256) {
      int i16 = e >> 8, c = e & 255;
      y_s[i16 * 260 + c] = yeb[((size_t)b * L + idx_s[tile * 16 + i16]) * 256 + c];
    }
    __syncthreads();
    size_t tb = (size_t)b * L * 256 + (size_t)((i0 >> 4) + tile) * 4096;
    for (int e = t; e < 4096; e += 256) {
      int c = e >> 4, k16 = e & 15;
      int sw = ((((k16 >> 2) ^ ((c >> 2) & 3)) << 2) | (k16 & 3));
      yt[tb + c * 16 + sw] = y_s[k16 * 260 + c];
    }
    __syncthreads();
  }
}

// ---------------- K6: flash MFMA attention ----------------
// grid (512) linear: b = i&7 (XCD affinity), k = i>>3. 576 thr = 9 waves, wave w owns
// queries kbase + w*16. K/V staged ONCE per window (was 3x). Defer-max THR=8.
__global__ __launch_bounds__(576, 1) void k_attn(const unsigned short* __restrict__ xk,
                                                 const unsigned short* __restrict__ yt,
                                                 const float* __restrict__ norms,
                                                 const int* __restrict__ sidx,
                                                 float* __restrict__ retb) {
  int i = blockIdx.x;
  int b = i & 7, k = i >> 3;
  __shared__ __align__(16) char lds[40960];
  int t = threadIdx.x;
  int lane = t & 63;
  int g = lane >> 4, kr = lane & 15;
  int kbase = k * WIN;
  int qr0 = kbase + (t >> 6) * 16;
  int qrow = qr0 + kr;

  s8v qf[2];
#pragma unroll
  for (int s = 0; s < 2; ++s) {
    int blk = (4 * s + g) ^ (qrow & 7);
    qf[s] = *(const s8v*)(xk + ((size_t)b * L + qrow) * 64 + blk * 8);
  }
  float qn = norms[(size_t)b * L + qrow];

  f32x4 acc[16];
#pragma unroll
  for (int nf = 0; nf < 16; ++nf) acc[nf] = (f32x4){0.f, 0.f, 0.f, 0.f};
  float runm = -3e38f, runsum = 0.f;

  auto stage = [&](int c, int buf) {
    char* kb = lds + buf * 20480;
    char* vb = kb + 4096;
    for (int e = t; e < 1280; e += 576) {
      if (e < 256) {
        int key32 = e >> 3;
        if (c == 13 && key32 >= 16) continue;
        int j = c * 32 + key32;
        int r = (j >= 288) ? 2 : (j >= 144) ? 1 : 0;
        int kk = (r == 0) ? k : (r == 1) ? ((k + 63) & 63) : ((k + 1) & 63);
        int phys = kk * WIN + (j - r * 144);
        const char* gp = (const char*)xk + (((size_t)b * L + phys) * 64 + (e & 7) * 8) * 2;
        __builtin_amdgcn_global_load_lds((const __attribute__((address_space(1))) void*)gp,
                                         (__attribute__((address_space(3))) void*)(kb + e * 16),
                                         16, 0, 0);
      } else {
        int u = e - 256;
        int f = u >> 9;
        if (c == 13 && f == 1) continue;
        int j0 = c * 32 + f * 16;
        int r = (j0 >= 288) ? 2 : (j0 >= 144) ? 1 : 0;
        int kk = (r == 0) ? k : (r == 1) ? ((k + 63) & 63) : ((k + 1) & 63);
        int rowbase = kk * WIN + (j0 - r * 144);
        const char* gp = (const char*)yt + ((size_t)b * L + rowbase) * 512 + (size_t)(u & 511) * 16;
        __builtin_amdgcn_global_load_lds((const __attribute__((address_space(1))) void*)gp,
                                         (__attribute__((address_space(3))) void*)(vb + u * 16),
                                         16, 0, 0);
      }
    }
  };

  auto compute = [&](int c, int buf) {
    char* kb = lds + buf * 20480;
    char* vb = kb + 4096;
    int nm = (c == 13) ? 1 : 2;
    f32x4 sa[2];
    sa[0] = (f32x4){0.f, 0.f, 0.f, 0.f};
    sa[1] = (f32x4){0.f, 0.f, 0.f, 0.f};
#pragma unroll
    for (int m = 0; m < 2; ++m)
      if (m < nm) {
        int row32 = m * 16 + kr;
#pragma unroll
        for (int s = 0; s < 2; ++s) {
          int off = row32 * 128 + (((4 * s + g) ^ (row32 & 7)) * 16);
          s8v kf = *(const s8v*)(kb + off);
          sa[m] = __builtin_amdgcn_mfma_f32_16x16x32_bf16(kf, qf[s], sa[m], 0, 0, 0);
        }
      }
    float p[2][4];
    float mx = -3e38f;
#pragma unroll
    for (int m = 0; m < 2; ++m)
#pragma unroll
      for (int r = 0; r < 4; ++r) {
        float v = (m < nm) ? sa[m][r] * qn : -3e38f;
        p[m][r] = v;
        mx = fmaxf(mx, v);
      }
    mx = fmaxf(mx, __shfl_xor(mx, 16));
    mx = fmaxf(mx, __shfl_xor(mx, 32));
    // defer-max: only rescale when the max grew by more than THR=8
    if (!__all(mx <= runm + 8.f)) {
      float newm = fmaxf(runm, mx);
      float corr = __expf(runm - newm);
      runm = newm;
      runsum *= corr;
      float f0 = __shfl(corr, 4 * g + 0);
      float f1 = __shfl(corr, 4 * g + 1);
      float f2 = __shfl(corr, 4 * g + 2);
      float f3 = __shfl(corr, 4 * g + 3);
#pragma unroll
      for (int nf = 0; nf < 16; ++nf) {
        acc[nf][0] *= f0; acc[nf][1] *= f1; acc[nf][2] *= f2; acc[nf][3] *= f3;
      }
    }
    float psum = 0.f;
#pragma unroll
    for (int m = 0; m < 2; ++m)
#pragma unroll
      for (int r = 0; r < 4; ++r) {
        float pv = __expf(p[m][r] - runm);
        p[m][r] = pv;
        psum += pv;
      }
    runsum += psum;
    s8v pa;
#pragma unroll
    for (int e2 = 0; e2 < 8; ++e2) pa[e2] = f2bf(p[e2 >> 2][e2 & 3]);
#pragma unroll
    for (int nf = 0; nf < 16; ++nf) {
      int cch = nf * 16 + kr;
      int grp = g ^ ((cch >> 2) & 3);
      s4v lo = *(const s4v*)(vb + cch * 32 + grp * 8);
      s4v hi = *(const s4v*)(vb + 8192 + cch * 32 + grp * 8);
      s8v bfv = __builtin_shufflevector(lo, hi, 0, 1, 2, 3, 4, 5, 6, 7);
      acc[nf] = __builtin_amdgcn_mfma_f32_16x16x32_bf16(pa, bfv, acc[nf], 0, 0, 0);
    }
  };

  stage(0, 0);
  __syncthreads();
  for (int c = 0; c < 14; ++c) {
    if (c < 13) stage(c + 1, (c + 1) & 1);
    compute(c, c & 1);
    __syncthreads();
  }

  runsum += __shfl_xor(runsum, 16);
  runsum += __shfl_xor(runsum, 32);
  float inv = 1.0f / runsum;
  float invr[4];
  int lorig[4];
#pragma unroll
  for (int r = 0; r < 4; ++r) {
    invr[r] = __shfl(inv, 4 * g + r);
    lorig[r] = sidx[b * L + qr0 + 4 * g + r];
  }
#pragma unroll
  for (int nf = 0; nf < 16; ++nf)
#pragma unroll
    for (int r = 0; r < 4; ++r)
      retb[((size_t)b * L + lorig[r]) * 256 + nf * 16 + kr] = acc[nf][r] * invr[r];
}

// ---------------- K7: transpose + residual ----------------
__global__ __launch_bounds__(256) void k_final(const float* __restrict__ in,
                                               const float* __restrict__ retb,
                                               float* __restrict__ out) {
  int lt = blockIdx.x, ct = blockIdx.y, b = blockIdx.z;
  int l0 = lt * 32, c0 = ct * 32;
  __shared__ float t_s[32][33];
  int t = threadIdx.x;
  for (int e = t; e < 1024; e += 256) {
    int i = e >> 5, j = e & 31;
    t_s[i][j] = retb[((size_t)b * L + l0 + i) * 256 + c0 + j];
  }
  __syncthreads();
  for (int e = t; e < 1024; e += 256) {
    int ci = e >> 5, lj = e & 31;
    size_t o = ((size_t)b * CC + c0 + ci) * L + l0 + lj;
    out[o] = in[o] + 0.1f * t_s[lj][ci];
  }
}

extern "C" void kernel_launch(void* const* d_in, const int* in_sizes, int n_in,
                              void* d_out, int out_size, void* d_ws, size_t ws_size,
                              hipStream_t stream) {
  const float* input = (const float*)d_in[0];
  const float* wm = (const float*)d_in[1];
  const float* bm = (const float*)d_in[2];
  const float* wa = (const float*)d_in[3];
  const float* ba = (const float*)d_in[4];
  const float* means = (const float*)d_in[5];
  float* out = (float*)d_out;

  float* ws = (float*)d_ws;
  float* x_embed = ws;                                      // 4,718,592 f
  float* y_embed = ws + 4718592ull;                         // 18,874,368 f (aliased: xhi/yeb, retb)
  float* retb = y_embed;
  unsigned short* xk = (unsigned short*)(ws + 23592960ull); // 4,718,592 bf16 (aliased: w bufs)
  unsigned short* yt = (unsigned short*)(ws + 25952256ull); // 18,874,368 bf16
  float* norms = ws + 35389440ull;                          // 73,728 f
  int* buckets = (int*)(ws + 35463168ull);                  // 73,728 i
  int* sidx = buckets + 73728;                              // 73,728 i
  unsigned short* xhi = (unsigned short*)y_embed;           // 18,874,368 bf16 (first half)
  unsigned short* xlo = xhi + 18874368ull;                  // second half; becomes yeb
  unsigned short* yeb = xlo;
  unsigned short* whiB = xk;                                // 294,912 bf16
  unsigned short* wloB = whiB + 294912ull;                  // 294,912 bf16
  unsigned short* wt1 = wloB + 294912ull;                   // 65,536 bf16

  k_isplit<<<dim3(96, 16, 8), 256, 0, stream>>>(input, xhi, xlo);
  k_wsplit<<<dim3(576), 256, 0, stream>>>(wm, whiB, wloB);
  k_w1prep<<<dim3(256), 256, 0, stream>>>(wa, wt1);
  k_conv3<<<dim3(96, 8), 384, 0, stream>>>(xhi, xlo, whiB, wloB, bm, x_embed);
  k_conv1<<<dim3(96, 8), 384, 0, stream>>>(xhi, wt1, ba, yeb);
  k_bucket<<<dim3(288, 8), 256, 0, stream>>>(x_embed, means, buckets);
  k_sort<<<dim3(8), 256, 0, stream>>>(buckets, sidx);
  k_gather<<<dim3(144, 8), 256, 0, stream>>>(x_embed, yeb, sidx, xk, yt, norms);
  k_attn<<<dim3(512), 576, 0, stream>>>(xk, yt, norms, sidx, retb);
  k_final<<<dim3(288, 8, 8), 256, 0, stream>>>(input, retb, out);
}

// Round 13
// 297.205 us; speedup vs baseline: 19.3319x; 1.0320x over previous
//
#include <hip/hip_runtime.h>
#include <math.h>

#define L 9216
#define HH 96
#define WW 96
#define CC 256
#define CR 64
#define NCLUST 128
#define WIN 144
#define NK 64   // L/WIN

typedef float f32x4 __attribute__((ext_vector_type(4)));
typedef float f32x16 __attribute__((ext_vector_type(16)));
typedef short s8v __attribute__((ext_vector_type(8)));
typedef short s4v __attribute__((ext_vector_type(4)));

static __device__ __forceinline__ short f2bf(float x) {
  union { float f; unsigned u; } v; v.f = x;
  unsigned r = (v.u + 0x7FFF + ((v.u >> 16) & 1)) >> 16;
  return (short)r;
}
static __device__ __forceinline__ float bf2f(short h) {
  union { float f; unsigned u; } v;
  v.u = ((unsigned)(unsigned short)h) << 16;
  return v.f;
}

// ---------------- K0a: input split fp32 -> xhi/xlo bf16, layout [b][h][icc16][w96][ic16] ----------------
__global__ __launch_bounds__(256) void k_isplit(const float* __restrict__ in,
                                                unsigned short* __restrict__ xhi,
                                                unsigned short* __restrict__ xlo) {
  int h = blockIdx.x, icc = blockIdx.y, b = blockIdx.z;
  __shared__ float tile[16][97];
  int t = threadIdx.x;
  for (int e = t; e < 1536; e += 256) {
    int ic = e / 96, w = e % 96;
    tile[ic][w] = in[((size_t)(b * 256 + icc * 16 + ic)) * L + h * 96 + w];
  }
  __syncthreads();
  size_t base = (((size_t)b * 96 + h) * 16 + icc) * 1536;
  for (int e = t; e < 1536; e += 256) {
    int w = e >> 4, ic = e & 15;
    float v = tile[ic][w];
    short hi = f2bf(v);
    float rv = v - bf2f(hi);
    short lo = f2bf(rv);
    xhi[base + e] = (unsigned short)hi;
    xlo[base + e] = (unsigned short)lo;
  }
}

// ---------------- K0b: conv3 weight split -> whiB/wloB [icc][tap][oc64][ic16] bf16 ----------------
__global__ __launch_bounds__(256) void k_wsplit(const float* __restrict__ wm,
                                                unsigned short* __restrict__ whiB,
                                                unsigned short* __restrict__ wloB) {
  int idx = blockIdx.x * 256 + threadIdx.x;
  if (idx < 147456) {
    int ic = idx & 15;
    int oc = (idx >> 4) & 63;
    int g = idx >> 10;
    int tap = g % 9, icc = g / 9;
    float v = wm[(size_t)oc * 2304 + (icc * 16 + ic) * 9 + tap];
    short hi = f2bf(v);
    float rv = v - bf2f(hi);
    whiB[idx] = (unsigned short)hi;
    wloB[idx] = (unsigned short)f2bf(rv);
  }
}

// ---------------- K0c: conv1 weight prep -> wt1 [icc][oc256][ic16] bf16 ----------------
__global__ __launch_bounds__(256) void k_w1prep(const float* __restrict__ wa,
                                                unsigned short* __restrict__ wt1) {
  int idx = blockIdx.x * 256 + threadIdx.x;  // 65536 total
  int ic = idx & 15, oc = (idx >> 4) & 255, icc = idx >> 12;
  wt1[idx] = (unsigned short)f2bf(wa[(size_t)oc * 256 + icc * 16 + ic]);
}

// ---------------- K1: conv3x3 via MFMA (split-bf16, 3 products) ----------------
// grid 768 linear: b = i&7 (XCD affinity), h = i>>3. 192 thr = 3 waves; wave pt owns
// 32 px x 64 oc (acc0: oc 0..31, acc1: oc 32..63). LDS: input only, dbuf 37.6 KB.
__global__ __launch_bounds__(192) void k_conv3(const unsigned short* __restrict__ xhi,
                                               const unsigned short* __restrict__ xlo,
                                               const unsigned short* __restrict__ whiB,
                                               const unsigned short* __restrict__ wloB,
                                               const float* __restrict__ bm,
                                               float* __restrict__ xe) {
  int i = blockIdx.x;
  int b = i & 7, h = i >> 3;
  __shared__ __align__(16) unsigned short lds[2 * 2 * 3 * 98 * 16];  // 37632 B
  int t = threadIdx.x;
  int pt = t >> 6, lane = t & 63;
  int hh = lane >> 5, j = lane & 31;
  int r = lane & 31;

  // zero the halo column slots (0 and 97) of all 2x2x3 planes
  for (int e = t; e < 384; e += 192) {
    int slot = e >> 4, ic = e & 15;
    int bs = slot / 6, rem = slot % 6;
    int rr = rem >> 1, cc = rem & 1;
    lds[bs * 4704 + rr * 1568 + (cc ? 97 : 0) * 16 + ic] = 0;
  }

  f32x16 acc0 = {}, acc1 = {};

  auto stage = [&](int icc, int buf) {
#pragma unroll
    for (int k6 = 0; k6 < 6; ++k6) {
      int u = t + k6 * 192;
      int s = u / 576;
      int rem = u - s * 576;
      int rr = rem / 192;
      int q = rem - rr * 192;
      int gr = h - 1 + rr;
      unsigned short* dst = &lds[(buf * 2 + s) * 4704 + rr * 1568 + 16 + q * 8];
      if (gr >= 0 && gr < 96) {
        const unsigned short* src =
            (s ? xlo : xhi) + ((((size_t)b * 96 + gr) * 16 + icc) * 1536 + q * 8);
        __builtin_amdgcn_global_load_lds((const __attribute__((address_space(1))) void*)src,
                                         (__attribute__((address_space(3))) void*)dst, 16, 0, 0);
      } else {
        *(s8v*)dst = (s8v){0, 0, 0, 0, 0, 0, 0, 0};
      }
    }
  };

  auto compute = [&](int icc, int buf) {
    const unsigned short* lbase = lds + buf * 9408;
    const unsigned short* wb = whiB + (size_t)icc * 9216;
    const unsigned short* wl = wloB + (size_t)icc * 9216;
#pragma unroll
    for (int kh = 0; kh < 3; ++kh)
#pragma unroll
      for (int kw = 0; kw < 3; ++kw) {
        int tap = kh * 3 + kw;
        int aidx = kh * 1568 + (pt * 32 + r + kw) * 16 + hh * 8;
        s8v a_hi = *(const s8v*)(lbase + aidx);
        s8v a_lo = *(const s8v*)(lbase + 4704 + aidx);
        int woff = tap * 1024 + j * 16 + hh * 8;
        s8v b_hi0 = *(const s8v*)(wb + woff);
        s8v b_lo0 = *(const s8v*)(wl + woff);
        s8v b_hi1 = *(const s8v*)(wb + woff + 512);
        s8v b_lo1 = *(const s8v*)(wl + woff + 512);
        acc0 = __builtin_amdgcn_mfma_f32_32x32x16_bf16(a_hi, b_hi0, acc0, 0, 0, 0);
        acc0 = __builtin_amdgcn_mfma_f32_32x32x16_bf16(a_hi, b_lo0, acc0, 0, 0, 0);
        acc0 = __builtin_amdgcn_mfma_f32_32x32x16_bf16(a_lo, b_hi0, acc0, 0, 0, 0);
        acc1 = __builtin_amdgcn_mfma_f32_32x32x16_bf16(a_hi, b_hi1, acc1, 0, 0, 0);
        acc1 = __builtin_amdgcn_mfma_f32_32x32x16_bf16(a_hi, b_lo1, acc1, 0, 0, 0);
        acc1 = __builtin_amdgcn_mfma_f32_32x32x16_bf16(a_lo, b_hi1, acc1, 0, 0, 0);
      }
  };

  stage(0, 0);
  __syncthreads();
#pragma unroll 1
  for (int icc = 0; icc < 16; ++icc) {
    int buf = icc & 1;
    if (icc < 15) stage(icc + 1, buf ^ 1);
    compute(icc, buf);
    __syncthreads();
  }

  float bv0 = bm[j], bv1 = bm[32 + j];
#pragma unroll
  for (int reg = 0; reg < 16; ++reg) {
    int prow = (reg & 3) + 8 * (reg >> 2) + 4 * hh;
    size_t rowbase = ((size_t)b * L + h * 96 + pt * 32 + prow) * 64;
    xe[rowbase + j] = acc0[reg] + bv0;
    xe[rowbase + 32 + j] = acc1[reg] + bv1;
  }
}

// ---------------- K2: conv1x1 via MFMA bf16 (no LDS, no barriers) ----------------
__global__ __launch_bounds__(384) void k_conv1(const unsigned short* __restrict__ xhi,
                                               const unsigned short* __restrict__ wt1,
                                               const float* __restrict__ ba,
                                               unsigned short* __restrict__ yeb) {
  int h = blockIdx.x, b = blockIdx.y;
  int t = threadIdx.x;
  int wave = t >> 6, lane = t & 63;
  int pt = wave % 3, ot = wave / 3;
  int hh = lane >> 5, j = lane & 31;
  int r = lane & 31;

  f32x16 acc[4] = {};
  const unsigned short* abase =
      xhi + (((size_t)b * 96 + h) * 16) * 1536 + (pt * 32 + r) * 16 + hh * 8;
  const unsigned short* bbase = wt1 + (ot * 128 + j) * 16 + hh * 8;
#pragma unroll 2
  for (int icc = 0; icc < 16; ++icc) {
    s8v av = *(const s8v*)(abase + icc * 1536);
    const unsigned short* bp = bbase + icc * 4096;
#pragma unroll
    for (int tile = 0; tile < 4; ++tile) {
      s8v bv = *(const s8v*)(bp + tile * 512);
      acc[tile] = __builtin_amdgcn_mfma_f32_32x32x16_bf16(av, bv, acc[tile], 0, 0, 0);
    }
  }
#pragma unroll
  for (int tile = 0; tile < 4; ++tile) {
    int oc = ot * 128 + tile * 32 + j;
    float bias = ba[oc];
#pragma unroll
    for (int reg = 0; reg < 16; ++reg) {
      int prow = (reg & 3) + 8 * (reg >> 2) + 4 * hh;
      yeb[((size_t)b * L + h * 96 + pt * 32 + prow) * 256 + oc] =
          (unsigned short)f2bf(acc[tile][reg] + bias);
    }
  }
}

// ---------------- K3: buckets = argmax_c(x . mean_c) ----------------
__global__ __launch_bounds__(256) void k_bucket(const float* __restrict__ xe,
                                                const float* __restrict__ means,
                                                int* __restrict__ buckets) {
  int lt = blockIdx.x, b = blockIdx.y;
  int l0 = lt * 32;
  __shared__ float x_s[32 * 65];
  __shared__ float m_s[128 * 65];
  __shared__ float bv_s[32 * 8];
  __shared__ int bi_s[32 * 8];
  int t = threadIdx.x;
  for (int e = t; e < 2048; e += 256) {
    int px = e >> 6, d = e & 63;
    x_s[px * 65 + d] = xe[((size_t)b * L + l0) * 64 + e];
  }
  for (int e = t; e < 8192; e += 256) {
    int c = e >> 6, d = e & 63;
    m_s[c * 65 + d] = means[e];
  }
  __syncthreads();
  int px = t >> 3, cg = t & 7;
  float best = -1e30f;
  int bidx = 0;
  const float* xr = &x_s[px * 65];
  for (int cc = 0; cc < 16; ++cc) {
    int c = cg + 8 * cc;
    const float* mr = &m_s[c * 65];
    float d = 0.f;
#pragma unroll
    for (int dd = 0; dd < 64; ++dd) d += xr[dd] * mr[dd];
    if (d > best || (d == best && c < bidx)) { best = d; bidx = c; }
  }
  bv_s[px * 8 + cg] = best;
  bi_s[px * 8 + cg] = bidx;
  __syncthreads();
  if (cg == 0) {
    float bb = bv_s[px * 8];
    int bbi = bi_s[px * 8];
    for (int g = 1; g < 8; ++g) {
      float v = bv_s[px * 8 + g];
      int vi = bi_s[px * 8 + g];
      if (v > bb || (v == bb && vi < bbi)) { bb = v; bbi = vi; }
    }
    buckets[b * L + l0 + px] = bbi;
  }
}

// ---------------- K4: parallel stable counting sort ----------------
#define SCH 256
#define CHL 36
__global__ __launch_bounds__(256) void k_sort(const int* __restrict__ buckets,
                                              int* __restrict__ sidx) {
  int b = blockIdx.x, t = threadIdx.x;
  __shared__ int keys_s[L];
  __shared__ unsigned short cnt_s[SCH][130];
  __shared__ int halfsum0[NCLUST];
  __shared__ int keytotal[NCLUST];
  __shared__ int keybase[NCLUST];
  const int* bk = buckets + b * L;
  for (int i = t; i < L; i += SCH) keys_s[i] = bk[i];
  for (int i = 0; i < 130; ++i) cnt_s[t][i] = 0;
  __syncthreads();
  {
    int base = t * CHL;
    for (int i = 0; i < CHL; ++i) cnt_s[t][keys_s[base + i]]++;
  }
  __syncthreads();
  {
    int kkey = t & 127, h = t >> 7;
    int c0 = h * 128;
    int run = 0;
    for (int c = 0; c < 128; ++c) {
      int v = cnt_s[c0 + c][kkey];
      cnt_s[c0 + c][kkey] = (unsigned short)run;
      run += v;
    }
    if (h == 0) halfsum0[kkey] = run;
    else keytotal[kkey] = run;
  }
  __syncthreads();
  if (t < NCLUST) keytotal[t] += halfsum0[t];
  __syncthreads();
  if (t == 0) {
    int s = 0;
    for (int i = 0; i < NCLUST; ++i) { keybase[i] = s; s += keytotal[i]; }
  }
  __syncthreads();
  {
    int h = t >> 7;
    int base = t * CHL;
    int* sb = sidx + b * L;
    for (int i = 0; i < CHL; ++i) {
      int kkey = keys_s[base + i];
      int pos = keybase[kkey] + (h ? halfsum0[kkey] : 0) + cnt_s[t][kkey];
      cnt_s[t][kkey]++;
      sb[pos] = base + i;
    }
  }
}

// ---------------- K5: gather + normalize -> xk (bf16 swizzled), yt (bf16 V^T tiles) ----------------
__global__ __launch_bounds__(256) void k_gather(const float* __restrict__ xe,
                                                const unsigned short* __restrict__ yeb,
                                                const int* __restrict__ sidx,
                                                unsigned short* __restrict__ xk,
                                                unsigned short* __restrict__ yt,
                                                float* __restrict__ norms) {
  int it = blockIdx.x, b = blockIdx.y;
  int i0 = it * 64;
  __shared__ float x_s[64 * 65];
  __shared__ unsigned short y_s[16 * 260];
  __shared__ int idx_s[64];
  __shared__ float scale_s[64];
  int t = threadIdx.x;
  if (t < 64) idx_s[t] = sidx[b * L + i0 + t];
  __syncthreads();
  for (int e = t; e < 4096; e += 256) {
    int i = e >> 6, d = e & 63;
    x_s[i * 65 + d] = xe[((size_t)b * L + idx_s[i]) * 64 + d];
  }
  __syncthreads();
  if (t < 64) {
    float s = 0.f;
    const float* xr = &x_s[t * 65];
#pragma unroll
    for (int d = 0; d < 64; ++d) s += xr[d] * xr[d];
    float n = fmaxf(sqrtf(s), 5e-5f);
    norms[b * L + i0 + t] = n;
    scale_s[t] = 1.0f / n;
  }
  __syncthreads();
  for (int e = t; e < 4096; e += 256) {
    int i = e >> 6, d = e & 63;
    int ig = i0 + i;
    int db = (((d >> 3) ^ (ig & 7)) << 3) | (d & 7);
    xk[((size_t)b * L + ig) * 64 + db] = (unsigned short)f2bf(x_s[i * 65 + d] * scale_s[i]);
  }
  for (int tile = 0; tile < 4; ++tile) {
    for (int e = t; e < 4096; e += 256) {
      int i16 = e >> 8, c = e & 255;
      y_s[i16 * 260 + c] = yeb[((size_t)b * L + idx_s[tile * 16 + i16]) * 256 + c];
    }
    __syncthreads();
    size_t tb = (size_t)b * L * 256 + (size_t)((i0 >> 4) + tile) * 4096;
    for (int e = t; e < 4096; e += 256) {
      int c = e >> 4, k16 = e & 15;
      int sw = ((((k16 >> 2) ^ ((c >> 2) & 3)) << 2) | (k16 & 3));
      yt[tb + c * 16 + sw] = y_s[k16 * 260 + c];
    }
    __syncthreads();
  }
}

// ---------------- K6: flash MFMA attention ----------------
// grid (512) linear: b = i&7 (XCD affinity), k = i>>3. 576 thr = 9 waves, wave w owns
// queries kbase + w*16. K/V staged ONCE per window. Defer-max THR=8.
__global__ __launch_bounds__(576, 1) void k_attn(const unsigned short* __restrict__ xk,
                                                 const unsigned short* __restrict__ yt,
                                                 const float* __restrict__ norms,
                                                 const int* __restrict__ sidx,
                                                 float* __restrict__ retb) {
  int i = blockIdx.x;
  int b = i & 7, k = i >> 3;
  __shared__ __align__(16) char lds[40960];
  int t = threadIdx.x;
  int lane = t & 63;
  int g = lane >> 4, kr = lane & 15;
  int kbase = k * WIN;
  int qr0 = kbase + (t >> 6) * 16;
  int qrow = qr0 + kr;

  s8v qf[2];
#pragma unroll
  for (int s = 0; s < 2; ++s) {
    int blk = (4 * s + g) ^ (qrow & 7);
    qf[s] = *(const s8v*)(xk + ((size_t)b * L + qrow) * 64 + blk * 8);
  }
  float qn = norms[(size_t)b * L + qrow];

  f32x4 acc[16];
#pragma unroll
  for (int nf = 0; nf < 16; ++nf) acc[nf] = (f32x4){0.f, 0.f, 0.f, 0.f};
  float runm = -3e38f, runsum = 0.f;

  auto stage = [&](int c, int buf) {
    char* kb = lds + buf * 20480;
    char* vb = kb + 4096;
    for (int e = t; e < 1280; e += 576) {
      if (e < 256) {
        int key32 = e >> 3;
        if (c == 13 && key32 >= 16) continue;
        int j = c * 32 + key32;
        int r = (j >= 288) ? 2 : (j >= 144) ? 1 : 0;
        int kk = (r == 0) ? k : (r == 1) ? ((k + 63) & 63) : ((k + 1) & 63);
        int phys = kk * WIN + (j - r * 144);
        const char* gp = (const char*)xk + (((size_t)b * L + phys) * 64 + (e & 7) * 8) * 2;
        __builtin_amdgcn_global_load_lds((const __attribute__((address_space(1))) void*)gp,
                                         (__attribute__((address_space(3))) void*)(kb + e * 16),
                                         16, 0, 0);
      } else {
        int u = e - 256;
        int f = u >> 9;
        if (c == 13 && f == 1) continue;
        int j0 = c * 32 + f * 16;
        int r = (j0 >= 288) ? 2 : (j0 >= 144) ? 1 : 0;
        int kk = (r == 0) ? k : (r == 1) ? ((k + 63) & 63) : ((k + 1) & 63);
        int rowbase = kk * WIN + (j0 - r * 144);
        const char* gp = (const char*)yt + ((size_t)b * L + rowbase) * 512 + (size_t)(u & 511) * 16;
        __builtin_amdgcn_global_load_lds((const __attribute__((address_space(1))) void*)gp,
                                         (__attribute__((address_space(3))) void*)(vb + u * 16),
                                         16, 0, 0);
      }
    }
  };

  auto compute = [&](int c, int buf) {
    char* kb = lds + buf * 20480;
    char* vb = kb + 4096;
    int nm = (c == 13) ? 1 : 2;
    f32x4 sa[2];
    sa[0] = (f32x4){0.f, 0.f, 0.f, 0.f};
    sa[1] = (f32x4){0.f, 0.f, 0.f, 0.f};
#pragma unroll
    for (int m = 0; m < 2; ++m)
      if (m < nm) {
        int row32 = m * 16 + kr;
#pragma unroll
        for (int s = 0; s < 2; ++s) {
          int off = row32 * 128 + (((4 * s + g) ^ (row32 & 7)) * 16);
          s8v kf = *(const s8v*)(kb + off);
          sa[m] = __builtin_amdgcn_mfma_f32_16x16x32_bf16(kf, qf[s], sa[m], 0, 0, 0);
        }
      }
    float p[2][4];
    float mx = -3e38f;
#pragma unroll
    for (int m = 0; m < 2; ++m)
#pragma unroll
      for (int r = 0; r < 4; ++r) {
        float v = (m < nm) ? sa[m][r] * qn : -3e38f;
        p[m][r] = v;
        mx = fmaxf(mx, v);
      }
    mx = fmaxf(mx, __shfl_xor(mx, 16));
    mx = fmaxf(mx, __shfl_xor(mx, 32));
    if (!__all(mx <= runm + 8.f)) {
      float newm = fmaxf(runm, mx);
      float corr = __expf(runm - newm);
      runm = newm;
      runsum *= corr;
      float f0 = __shfl(corr, 4 * g + 0);
      float f1 = __shfl(corr, 4 * g + 1);
      float f2 = __shfl(corr, 4 * g + 2);
      float f3 = __shfl(corr, 4 * g + 3);
#pragma unroll
      for (int nf = 0; nf < 16; ++nf) {
        acc[nf][0] *= f0; acc[nf][1] *= f1; acc[nf][2] *= f2; acc[nf][3] *= f3;
      }
    }
    float psum = 0.f;
#pragma unroll
    for (int m = 0; m < 2; ++m)
#pragma unroll
      for (int r = 0; r < 4; ++r) {
        float pv = __expf(p[m][r] - runm);
        p[m][r] = pv;
        psum += pv;
      }
    runsum += psum;
    s8v pa;
#pragma unroll
    for (int e2 = 0; e2 < 8; ++e2) pa[e2] = f2bf(p[e2 >> 2][e2 & 3]);
#pragma unroll
    for (int nf = 0; nf < 16; ++nf) {
      int cch = nf * 16 + kr;
      int grp = g ^ ((cch >> 2) & 3);
      s4v lo = *(const s4v*)(vb + cch * 32 + grp * 8);
      s4v hi = *(const s4v*)(vb + 8192 + cch * 32 + grp * 8);
      s8v bfv = __builtin_shufflevector(lo, hi, 0, 1, 2, 3, 4, 5, 6, 7);
      acc[nf] = __builtin_amdgcn_mfma_f32_16x16x32_bf16(pa, bfv, acc[nf], 0, 0, 0);
    }
  };

  stage(0, 0);
  __syncthreads();
  for (int c = 0; c < 14; ++c) {
    if (c < 13) stage(c + 1, (c + 1) & 1);
    compute(c, c & 1);
    __syncthreads();
  }

  runsum += __shfl_xor(runsum, 16);
  runsum += __shfl_xor(runsum, 32);
  float inv = 1.0f / runsum;
  float invr[4];
  int lorig[4];
#pragma unroll
  for (int r = 0; r < 4; ++r) {
    invr[r] = __shfl(inv, 4 * g + r);
    lorig[r] = sidx[b * L + qr0 + 4 * g + r];
  }
#pragma unroll
  for (int nf = 0; nf < 16; ++nf)
#pragma unroll
    for (int r = 0; r < 4; ++r)
      retb[((size_t)b * L + lorig[r]) * 256 + nf * 16 + kr] = acc[nf][r] * invr[r];
}

// ---------------- K7: transpose + residual ----------------
__global__ __launch_bounds__(256) void k_final(const float* __restrict__ in,
                                               const float* __restrict__ retb,
                                               float* __restrict__ out) {
  int lt = blockIdx.x, ct = blockIdx.y, b = blockIdx.z;
  int l0 = lt * 32, c0 = ct * 32;
  __shared__ float t_s[32][33];
  int t = threadIdx.x;
  for (int e = t; e < 1024; e += 256) {
    int i = e >> 5, j = e & 31;
    t_s[i][j] = retb[((size_t)b * L + l0 + i) * 256 + c0 + j];
  }
  __syncthreads();
  for (int e = t; e < 1024; e += 256) {
    int ci = e >> 5, lj = e & 31;
    size_t o = ((size_t)b * CC + c0 + ci) * L + l0 + lj;
    out[o] = in[o] + 0.1f * t_s[lj][ci];
  }
}

extern "C" void kernel_launch(void* const* d_in, const int* in_sizes, int n_in,
                              void* d_out, int out_size, void* d_ws, size_t ws_size,
                              hipStream_t stream) {
  const float* input = (const float*)d_in[0];
  const float* wm = (const float*)d_in[1];
  const float* bm = (const float*)d_in[2];
  const float* wa = (const float*)d_in[3];
  const float* ba = (const float*)d_in[4];
  const float* means = (const float*)d_in[5];
  float* out = (float*)d_out;

  float* ws = (float*)d_ws;
  float* x_embed = ws;                                      // 4,718,592 f
  float* y_embed = ws + 4718592ull;                         // 18,874,368 f (aliased: xhi/yeb, retb)
  float* retb = y_embed;
  unsigned short* xk = (unsigned short*)(ws + 23592960ull); // 4,718,592 bf16 (aliased: w bufs)
  unsigned short* yt = (unsigned short*)(ws + 25952256ull); // 18,874,368 bf16
  float* norms = ws + 35389440ull;                          // 73,728 f
  int* buckets = (int*)(ws + 35463168ull);                  // 73,728 i
  int* sidx = buckets + 73728;                              // 73,728 i
  unsigned short* xhi = (unsigned short*)y_embed;           // 18,874,368 bf16 (first half)
  unsigned short* xlo = xhi + 18874368ull;                  // second half; becomes yeb
  unsigned short* yeb = xlo;
  unsigned short* whiB = xk;                                // 294,912 bf16
  unsigned short* wloB = whiB + 294912ull;                  // 294,912 bf16
  unsigned short* wt1 = wloB + 294912ull;                   // 65,536 bf16

  k_isplit<<<dim3(96, 16, 8), 256, 0, stream>>>(input, xhi, xlo);
  k_wsplit<<<dim3(576), 256, 0, stream>>>(wm, whiB, wloB);
  k_w1prep<<<dim3(256), 256, 0, stream>>>(wa, wt1);
  k_conv3<<<dim3(768), 192, 0, stream>>>(xhi, xlo, whiB, wloB, bm, x_embed);
  k_conv1<<<dim3(96, 8), 384, 0, stream>>>(xhi, wt1, ba, yeb);
  k_bucket<<<dim3(288, 8), 256, 0, stream>>>(x_embed, means, buckets);
  k_sort<<<dim3(8), 256, 0, stream>>>(buckets, sidx);
  k_gather<<<dim3(144, 8), 256, 0, stream>>>(x_embed, yeb, sidx, xk, yt, norms);
  k_attn<<<dim3(512), 576, 0, stream>>>(xk, yt, norms, sidx, retb);
  k_final<<<dim3(288, 8, 8), 256, 0, stream>>>(input, retb, out);
}